// Round 2
// baseline (315747.510 us; speedup 1.0000x reference)
//
#include <hip/hip_runtime.h>
#include <math.h>

#define DI __device__ __forceinline__

namespace {

constexpr int Bb = 4, Tt = 2048, Dd = 1024, Cc = 16, NCc = 128;
constexpr int DOUTS[6] = {1024, 1024, 1024, 1, 1, 1024};
constexpr int BIGM[4] = {0, 1, 2, 5};

constexpr long SZ_BIG = (long)Dd * Dd + (long)Dd * Dd + 1024 + 1024;
constexpr long SZ_SMALL = (long)Dd * Dd + 1024 + 1024 + 1024;
constexpr long MODOFF[6] = {0, SZ_BIG, 2 * SZ_BIG, 3 * SZ_BIG,
                            3 * SZ_BIG + SZ_SMALL, 3 * SZ_BIG + 2 * SZ_SMALL};
constexpr long BSTRIDE = 3 * SZ_BIG + 2 * SZ_SMALL + SZ_BIG;

constexpr long OFF_Z     = 0;
constexpr long OFF_STATE = OFF_Z + (long)Bb * Tt * Dd;
constexpr long OFF_PRE5  = OFF_STATE + 4 * BSTRIDE;
constexpr long OFF_KVQ   = OFF_PRE5 + (long)Bb * 5 * Cc * Dd;
constexpr long OFF_PREV  = OFF_KVQ + (long)Bb * 3 * Cc * Dd;
constexpr long OFF_PREK  = OFF_PREV + (long)Bb * 6 * Cc * Dd;
constexpr long OFF_PREO  = OFF_PREK + (long)Bb * 6 * Cc * Dd;
constexpr long OFF_ERR   = OFF_PREO + (long)Bb * Cc * Dd;
constexpr long OFF_DLP   = OFF_ERR + (long)Bb * 6 * Cc * Dd;
constexpr long OFF_RSSQ  = OFF_DLP + (long)Bb * 6 * Cc * Dd;   // [B][2][16]
constexpr long OFF_EA    = OFF_RSSQ + Bb * 2 * Cc;             // [0..3]=ea, [4..7]=aa
constexpr long OFF_SCALE = OFF_EA + 8;                         // 96
constexpr long OFF_SUMSQ = OFF_SCALE + 96;                     // 96
constexpr long OFF_INWT  = OFF_SUMSQ + 96;
constexpr long OFF_OUTWT = OFF_INWT + (long)Dd * Dd;
constexpr long WS_FLOATS = OFF_OUTWT + (long)Dd * Dd;

struct InPtrs { const float* p[31]; };

DI float* stateBase(float* ws, int b, int m) {
  return ws + OFF_STATE + (long)b * BSTRIDE + MODOFF[m];
}
DI int sidx(int b, int m, int p) { return ((b * 6 + m) << 2) + p; }
DI float maxnf(int m, int p) {
  switch (p) {
    case 0: return sqrtf((float)(Dd * DOUTS[m]));
    case 1: return sqrtf((float)DOUTS[m]);
    case 2: return 1024.0f;
    default: return 32.0f;
  }
}
DI float sigm(float x) { return 1.0f / (1.0f + expf(-x)); }
DI float silu(float x) { return x * sigm(x); }
DI float fcomp(const float4& v, int rr) {
  return rr == 0 ? v.x : (rr == 1 ? v.y : (rr == 2 ? v.z : v.w));
}

DI void sumsqReduce(float ss, float* slack, float* dst) {
#pragma unroll
  for (int st = 32; st >= 1; st >>= 1) ss += __shfl_xor(ss, st);
  const int tid = threadIdx.x;
  if ((tid & 63) == 0) slack[tid >> 6] = ss;
  __syncthreads();
  if (tid == 0) atomicAdd(dst, slack[0] + slack[1] + slack[2] + slack[3]);
  __syncthreads();
}

// ================== GEMM core v2 =====================================
// Y[16 c][64 n-cols] = sum_k X[c][k] * A[k][n],  A row-major [1024][1024].
// 512 threads = 8 waves. Wave g owns k rows [g*128, g*128+128) in 8 stages of
// 16 rows. Per stage: wave stages its private A-slice [16][64] into LDS via
// coalesced float4 (no cross-wave sharing -> no barriers in the k-loop), then
// FMAs with X read as wave-uniform (HW-broadcast) global loads.
// LDS: Ws[8][16*64] = 8192 floats, aliased after a barrier by the reduce
// buffers red[4][16*68+8].
constexpr int RST = 16 * 68 + 8;  // 1096 floats per reduce group

template <class XF, class EF>
DI void coreV2(float* sm, XF&& xf, const float* __restrict__ A, int n0, EF&& ef) {
  const int tid = threadIdx.x, g = tid >> 6, l = tid & 63;
  float* wbase = sm + g * 1024;
  const int lr = l >> 4, lc = (l & 15) * 4;
  float acc[16];
#pragma unroll
  for (int c = 0; c < 16; c++) acc[c] = 0.f;
#pragma unroll 1
  for (int st = 0; st < 8; st++) {
    const int kb = (g << 7) + (st << 4);
    const float* Ar = A + (size_t)(kb + lr) * Dd + n0 + lc;
    const float4 a0 = *reinterpret_cast<const float4*>(Ar);
    const float4 a1 = *reinterpret_cast<const float4*>(Ar + (size_t)4 * Dd);
    const float4 a2 = *reinterpret_cast<const float4*>(Ar + (size_t)8 * Dd);
    const float4 a3 = *reinterpret_cast<const float4*>(Ar + (size_t)12 * Dd);
    *reinterpret_cast<float4*>(&wbase[lr * 64 + lc]) = a0;
    *reinterpret_cast<float4*>(&wbase[(lr + 4) * 64 + lc]) = a1;
    *reinterpret_cast<float4*>(&wbase[(lr + 8) * 64 + lc]) = a2;
    *reinterpret_cast<float4*>(&wbase[(lr + 12) * 64 + lc]) = a3;
#pragma unroll
    for (int r4 = 0; r4 < 4; r4++) {
      const int k0 = kb + r4 * 4;
      float4 xq[16];
#pragma unroll
      for (int c = 0; c < 16; c++)
        xq[c] = make_float4(xf(c, k0), xf(c, k0 + 1), xf(c, k0 + 2), xf(c, k0 + 3));
#pragma unroll
      for (int rr = 0; rr < 4; rr++) {
        const float w = wbase[(r4 * 4 + rr) * 64 + l];
#pragma unroll
        for (int c = 0; c < 16; c++) acc[c] = fmaf(fcomp(xq[c], rr), w, acc[c]);
      }
    }
  }
  __syncthreads();
  if (g < 4) {
#pragma unroll
    for (int c = 0; c < 16; c++) sm[g * RST + c * 68 + l] = acc[c];
  }
  __syncthreads();
  if (g >= 4) {
#pragma unroll
    for (int c = 0; c < 16; c++) sm[(g - 4) * RST + c * 68 + l] += acc[c];
  }
  __syncthreads();
#pragma unroll
  for (int i = 0; i < 2; i++) {
    const int flat = tid * 2 + i, c = flat >> 6, n = flat & 63;
    const float v = sm[0 * RST + c * 68 + n] + sm[1 * RST + c * 68 + n] +
                    sm[2 * RST + c * 68 + n] + sm[3 * RST + c * 68 + n];
    ef(c, n0 + n, v);
  }
}

// dual-X variant: two X sets share one pass over A. X chunks of 2 rows (float2)
// to keep VGPR pressure down. reduce: red1 at sm+0, red2 at sm+4384.
template <class XF1, class XF2, class EF>
DI void coreV2d(float* sm, XF1&& xf1, XF2&& xf2, const float* __restrict__ A,
                int n0, EF&& ef) {
  const int tid = threadIdx.x, g = tid >> 6, l = tid & 63;
  float* wbase = sm + g * 1024;
  const int lr = l >> 4, lc = (l & 15) * 4;
  float acc1[16], acc2[16];
#pragma unroll
  for (int c = 0; c < 16; c++) { acc1[c] = 0.f; acc2[c] = 0.f; }
#pragma unroll 1
  for (int st = 0; st < 8; st++) {
    const int kb = (g << 7) + (st << 4);
    const float* Ar = A + (size_t)(kb + lr) * Dd + n0 + lc;
    const float4 a0 = *reinterpret_cast<const float4*>(Ar);
    const float4 a1 = *reinterpret_cast<const float4*>(Ar + (size_t)4 * Dd);
    const float4 a2 = *reinterpret_cast<const float4*>(Ar + (size_t)8 * Dd);
    const float4 a3 = *reinterpret_cast<const float4*>(Ar + (size_t)12 * Dd);
    *reinterpret_cast<float4*>(&wbase[lr * 64 + lc]) = a0;
    *reinterpret_cast<float4*>(&wbase[(lr + 4) * 64 + lc]) = a1;
    *reinterpret_cast<float4*>(&wbase[(lr + 8) * 64 + lc]) = a2;
    *reinterpret_cast<float4*>(&wbase[(lr + 12) * 64 + lc]) = a3;
#pragma unroll
    for (int r2 = 0; r2 < 8; r2++) {
      const int k0 = kb + r2 * 2;
      float2 x1[16], x2[16];
#pragma unroll
      for (int c = 0; c < 16; c++) {
        x1[c] = make_float2(xf1(c, k0), xf1(c, k0 + 1));
        x2[c] = make_float2(xf2(c, k0), xf2(c, k0 + 1));
      }
#pragma unroll
      for (int rr = 0; rr < 2; rr++) {
        const float w = wbase[(r2 * 2 + rr) * 64 + l];
#pragma unroll
        for (int c = 0; c < 16; c++) {
          acc1[c] = fmaf(rr == 0 ? x1[c].x : x1[c].y, w, acc1[c]);
          acc2[c] = fmaf(rr == 0 ? x2[c].x : x2[c].y, w, acc2[c]);
        }
      }
    }
  }
  float* red2 = sm + 4384;
  __syncthreads();
  if (g < 4) {
#pragma unroll
    for (int c = 0; c < 16; c++) {
      sm[g * RST + c * 68 + l] = acc1[c];
      red2[g * RST + c * 68 + l] = acc2[c];
    }
  }
  __syncthreads();
  if (g >= 4) {
#pragma unroll
    for (int c = 0; c < 16; c++) {
      sm[(g - 4) * RST + c * 68 + l] += acc1[c];
      red2[(g - 4) * RST + c * 68 + l] += acc2[c];
    }
  }
  __syncthreads();
#pragma unroll
  for (int i = 0; i < 2; i++) {
    const int flat = tid * 2 + i, c = flat >> 6, n = flat & 63;
    const float v1 = sm[0 * RST + c * 68 + n] + sm[1 * RST + c * 68 + n] +
                     sm[2 * RST + c * 68 + n] + sm[3 * RST + c * 68 + n];
    const float v2 = red2[0 * RST + c * 68 + n] + red2[1 * RST + c * 68 + n] +
                     red2[2 * RST + c * 68 + n] + red2[3 * RST + c * 68 + n];
    ef(c, n0 + n, v1, v2);
  }
}

// ============================ prologue ============================

__global__ __launch_bounds__(256) void k_p0(float* ws, InPtrs in) {
  const long i = threadIdx.x + (long)blockIdx.x * 256;
  if (i < 96) { ws[OFF_SCALE + i] = 1.f; return; }
  if (i < 192) { ws[OFF_SUMSQ + (i - 96)] = 0.f; return; }
  if (i < 320) { ws[OFF_RSSQ + (i - 192)] = 0.f; return; }
  const long j = i - 320;
  if (j < 24 * 2048) {
    const int bm = (int)(j >> 11), q = (int)(j & 2047);
    const int b = bm / 6, m = bm % 6;
    float* base = stateBase(ws, b, m);
    float* b1 = base + (long)Dd * Dd + (long)Dd * DOUTS[m];
    if (q < 1024) {
      if (q < DOUTS[m]) b1[q] = in.p[2 + 4 * m][q];
    } else {
      b1[1024 + (q - 1024)] = in.p[4 + 4 * m][q - 1024];
    }
    return;
  }
  const long j2 = j - 49152;
  if (j2 < 8192) {
    const int e = (int)(j2 >> 10), b = e >> 1, m = 3 + (e & 1);
    const int h = (int)(j2 & 1023);
    (stateBase(ws, b, m) + (long)Dd * Dd)[h] = in.p[1 + 4 * m][h];
  }
}

__global__ __launch_bounds__(256) void k_p1(float* ws, InPtrs in) {
  __shared__ float tile[64][65];
  const int bid = blockIdx.x, ti = bid & 255, j = bid >> 8;
  const int tr = (ti >> 4) << 6, tc = (ti & 15) << 6;
  const float* src; float* dst; int nb;
  if (j < 6) { src = in.p[3 + 4 * j]; dst = ws + OFF_STATE + MODOFF[j]; nb = 4; }
  else if (j < 10) { const int m = BIGM[j - 6]; src = in.p[1 + 4 * m]; dst = ws + OFF_STATE + MODOFF[m] + (long)Dd * Dd; nb = 4; }
  else if (j == 10) { src = in.p[25]; dst = ws + OFF_INWT; nb = 1; }
  else { src = in.p[27]; dst = ws + OFF_OUTWT; nb = 1; }
  const int l = threadIdx.x & 63, wq = threadIdx.x >> 6;
  for (int r = wq; r < 64; r += 4) tile[r][l] = src[(long)(tr + r) * Dd + tc + l];
  __syncthreads();
  for (int r = wq; r < 64; r += 4) {
    const float v = tile[l][r];
    for (int q = 0; q < nb; q++) dst[(long)q * BSTRIDE + (long)(tc + r) * Dd + tr + l] = v;
  }
}

__global__ __launch_bounds__(512) void k_gemm_big(const float* __restrict__ X,
                                                  const float* __restrict__ A,
                                                  const float* __restrict__ bias,
                                                  float* __restrict__ Y) {
  __shared__ float sm[8192];
  const int bid = blockIdx.x, tile = bid & 15;
  const long rb = bid >> 4;
  const float* Xr = X + rb * 16 * 1024;
  float* Yr = Y + rb * 16 * 1024;
  coreV2(sm, [&](int c, int k) { return Xr[(long)c * 1024 + k]; }, A, tile * 64,
         [&](int c, int n, float v) { Yr[(long)c * 1024 + n] = v + bias[n]; });
}

// ============================ per-step kernels ============================

__global__ __launch_bounds__(256) void k_s0(float* ws, int t) {
  const int i = threadIdx.x;
  if (i < 96) {
    const float ssv = ws[OFF_SUMSQ + i];
    const int p = i & 3, m = (i >> 2) % 6;
    ws[OFF_SCALE + i] = fminf(maxnf(m, p) / (sqrtf(ssv) + 1e-8f), 1.0f);
    ws[OFF_SUMSQ + i] = 0.f;
  } else if (i < 224) {
    ws[OFF_RSSQ + (i - 96)] = 0.f;
  }
  (void)t;
}

// S1: pre_m = cW2*(z @ W2T) + cb2*b2 for m in {k,v,q,eta,alpha}. grid 320x512.
__global__ __launch_bounds__(512) void k_s1(float* ws, int t) {
  __shared__ float sm[8192];
  const int bid = blockIdx.x, tile = bid & 15, m = (bid >> 4) % 5, b = bid / 80;
  const float* zc = ws + OFF_Z + ((long)b * Tt + (long)t * Cc) * Dd;
  const float* A = stateBase(ws, b, m);
  const float* scl = ws + OFF_SCALE;
  const float cW2 = scl[sidx(b, m, 2)], cb2 = scl[sidx(b, m, 3)];
  const float* b2 = stateBase(ws, b, m) + (long)Dd * Dd + (long)Dd * DOUTS[m] + 1024;
  float* Y = ws + OFF_PRE5 + ((long)b * 5 + m) * Cc * Dd;
  coreV2(sm, [&](int c, int k) { return zc[(long)c * Dd + k]; }, A, tile * 64,
         [&](int c, int n, float v) { Y[(long)c * Dd + n] = fmaf(cW2, v, cb2 * b2[n]); });
}

// S2: out_{k,v,q} = cW1*(silu(pre)@W1T) + cb1*b1 + z ; row-sumsq for k,q ;
// eta/alpha heads -> ea/aa. grid 200x512.
__global__ __launch_bounds__(512) void k_s2(float* ws, int t) {
  __shared__ float sm[8192 + 16];
  const int tid = threadIdx.x, bid = blockIdx.x;
  const float* scl = ws + OFF_SCALE;
  if (bid < 192) {
    const int tile = bid & 15, m = (bid >> 4) % 3, b = bid / 48;
    if (tid < 16) sm[8192 + tid] = 0.f;
    const float* pre = ws + OFF_PRE5 + ((long)b * 5 + m) * Cc * Dd;
    const float* A = stateBase(ws, b, m) + (long)Dd * Dd;
    const float* zc = ws + OFF_Z + ((long)b * Tt + (long)t * Cc) * Dd;
    const float cW1 = scl[sidx(b, m, 0)], cb1 = scl[sidx(b, m, 1)];
    const float* b1 = stateBase(ws, b, m) + (long)Dd * Dd + (long)Dd * DOUTS[m];
    float* out = ws + OFF_KVQ + ((long)b * 3 + m) * Cc * Dd;
    const bool sq = (m != 1);
    const int which = (m == 0) ? 0 : 1;
    coreV2(sm, [&](int c, int k) { return silu(pre[(long)c * Dd + k]); }, A, tile * 64,
           [&](int c, int n, float v) {
             const float val = fmaf(cW1, v, fmaf(cb1, b1[n], zc[(long)c * Dd + n]));
             out[(long)c * Dd + n] = val;
             if (sq) atomicAdd(&sm[8192 + c], val * val);
           });
    __syncthreads();
    if (sq && tid < 16)
      atomicAdd(ws + OFF_RSSQ + ((long)b * 2 + which) * Cc + tid, sm[8192 + tid]);
  } else {
    const int e = bid - 192, b = e >> 1, m = 3 + (e & 1);
    const float* pre = ws + OFF_PRE5 + ((long)b * 5 + m) * Cc * Dd;
    const float* w1 = stateBase(ws, b, m) + (long)Dd * Dd;
    float av[16];
#pragma unroll
    for (int c = 0; c < 16; c++) av[c] = 0.f;
#pragma unroll
    for (int jj = 0; jj < 2; jj++) {
      const int h = tid + 512 * jj;
      const float w = w1[h];
#pragma unroll
      for (int c = 0; c < 16; c++) av[c] = fmaf(silu(pre[(long)c * Dd + h]), w, av[c]);
    }
#pragma unroll
    for (int st = 1; st < 64; st <<= 1)
#pragma unroll
      for (int c = 0; c < 16; c++) av[c] += __shfl_xor(av[c], st);
    if ((tid & 63) == 0) {
      const int w8 = tid >> 6;
#pragma unroll
      for (int c = 0; c < 16; c++) sm[w8 * 16 + c] = av[c];
    }
    __syncthreads();
    if (tid == 0) {
      const float cW1 = scl[sidx(b, m, 0)], cb1 = scl[sidx(b, m, 1)];
      const float b10 = (stateBase(ws, b, m) + (long)Dd * Dd + 1024)[0];
      float s = 0.f;
      for (int c = 0; c < 16; c++) {
        float tot = 0.f;
        for (int w8 = 0; w8 < 8; w8++) tot += sm[w8 * 16 + c];
        s += sigm(fmaf(cW1, tot, cb1 * b10));
      }
      ws[OFF_EA + ((m == 3) ? 0 : 4) + b] = s * 0.0625f;
    }
  }
}

// S3: dual pass (X1=v, X2=k_norm) through every module's W2T, plus q_norm pass
// through memory's W2T. grid 448x512.
__global__ __launch_bounds__(512) void k_s3(float* ws) {
  __shared__ float sm[8768];
  const int bid = blockIdx.x;
  const float* scl = ws + OFF_SCALE;
  if (bid < 384) {
    const int tile = bid & 15, m = (bid >> 4) % 6, b = bid / 96;
    const float* rssq = ws + OFF_RSSQ + (long)b * 2 * Cc;
    float inv[16];
#pragma unroll
    for (int c = 0; c < 16; c++) inv[c] = 1.f / fmaxf(sqrtf(rssq[c]), 1e-12f);
    const float* vX = ws + OFF_KVQ + ((long)b * 3 + 1) * Cc * Dd;
    const float* kX = ws + OFF_KVQ + ((long)b * 3 + 0) * Cc * Dd;
    const float* A = stateBase(ws, b, m);
    const float cW2 = scl[sidx(b, m, 2)], cb2 = scl[sidx(b, m, 3)];
    const float* b2 = stateBase(ws, b, m) + (long)Dd * Dd + (long)Dd * DOUTS[m] + 1024;
    float* Yv = ws + OFF_PREV + ((long)b * 6 + m) * Cc * Dd;
    float* Yk = ws + OFF_PREK + ((long)b * 6 + m) * Cc * Dd;
    coreV2d(sm,
            [&](int c, int k) { return vX[(long)c * Dd + k]; },
            [&](int c, int k) { return kX[(long)c * Dd + k] * inv[c]; },
            A, tile * 64,
            [&](int c, int n, float v1, float v2) {
              const float bb = cb2 * b2[n];
              Yv[(long)c * Dd + n] = fmaf(cW2, v1, bb);
              Yk[(long)c * Dd + n] = fmaf(cW2, v2, bb);
            });
  } else {
    const int id = bid - 384, tile = id & 15, b = id >> 4;
    const float* rssq = ws + OFF_RSSQ + (long)b * 2 * Cc + 16;
    float inv[16];
#pragma unroll
    for (int c = 0; c < 16; c++) inv[c] = 1.f / fmaxf(sqrtf(rssq[c]), 1e-12f);
    const float* X = ws + OFF_KVQ + ((long)b * 3 + 2) * Cc * Dd;
    float* Y = ws + OFF_PREO + (long)b * Cc * Dd;
    const float* A = stateBase(ws, b, 5);
    const float cW2 = scl[sidx(b, 5, 2)], cb2 = scl[sidx(b, 5, 3)];
    const float* b2 = stateBase(ws, b, 5) + (long)Dd * Dd + (long)Dd * DOUTS[5] + 1024;
    coreV2(sm, [&](int c, int k) { return X[(long)c * Dd + k] * inv[c]; }, A, tile * 64,
           [&](int c, int n, float v) { Y[(long)c * Dd + n] = fmaf(cW2, v, cb2 * b2[n]); });
  }
}

// S4: big modules: v_hat & pred share one W1T pass -> error; memory output o ->
// z chunk; eta/alpha errors. grid 328x512.
__global__ __launch_bounds__(512) void k_s4(float* ws, int t) {
  __shared__ float sm[8768 + 16];
  const int tid = threadIdx.x, bid = blockIdx.x;
  const float* scl = ws + OFF_SCALE;
  if (bid < 256) {
    const int tile = bid & 15, mi = (bid >> 4) & 3, b = bid >> 6;
    const int m = BIGM[mi];
    if (tid < 16) {
      const float ssv = ws[OFF_RSSQ + (long)b * 2 * Cc + tid];
      sm[8768 + tid] = 1.f / fmaxf(sqrtf(ssv), 1e-12f);
    }
    const float* prev = ws + OFF_PREV + ((long)b * 6 + m) * Cc * Dd;
    const float* prek = ws + OFF_PREK + ((long)b * 6 + m) * Cc * Dd;
    const float* A = stateBase(ws, b, m) + (long)Dd * Dd;
    const float cW1 = scl[sidx(b, m, 0)], cb1 = scl[sidx(b, m, 1)];
    const float* b1 = stateBase(ws, b, m) + (long)Dd * Dd + (long)Dd * DOUTS[m];
    const float* vraw = ws + OFF_KVQ + ((long)b * 3 + 1) * Cc * Dd;
    const float* kraw = ws + OFF_KVQ + ((long)b * 3 + 0) * Cc * Dd;
    float* errP = ws + OFF_ERR + ((long)b * 6 + m) * Cc * Dd;
    coreV2d(sm,
            [&](int c, int k) { return silu(prev[(long)c * Dd + k]); },
            [&](int c, int k) { return silu(prek[(long)c * Dd + k]); },
            A, tile * 64,
            [&](int c, int n, float v1, float v2) {
              const float vh = fmaf(cW1, v1, fmaf(cb1, b1[n], vraw[(long)c * Dd + n]));
              const float pr = fmaf(cW1, v2, fmaf(cb1, b1[n], kraw[(long)c * Dd + n] * sm[8768 + c]));
              errP[(long)c * Dd + n] = (pr - vh) * 0.0625f;
            });
  } else if (bid < 320) {
    const int id = bid - 256, tile = id & 15, b = id >> 4;
    if (tid < 16) {
      const float ssv = ws[OFF_RSSQ + (long)b * 2 * Cc + 16 + tid];
      sm[8768 + tid] = 1.f / fmaxf(sqrtf(ssv), 1e-12f);
    }
    const float* preo = ws + OFF_PREO + (long)b * Cc * Dd;
    const float* A = stateBase(ws, b, 5) + (long)Dd * Dd;
    const float cW1 = scl[sidx(b, 5, 0)], cb1 = scl[sidx(b, 5, 1)];
    const float* b1 = stateBase(ws, b, 5) + (long)Dd * Dd + (long)Dd * DOUTS[5];
    const float* qraw = ws + OFF_KVQ + ((long)b * 3 + 2) * Cc * Dd;
    float* zc = ws + OFF_Z + ((long)b * Tt + (long)t * Cc) * Dd;
    coreV2(sm, [&](int c, int k) { return silu(preo[(long)c * Dd + k]); }, A, tile * 64,
           [&](int c, int n, float v) {
             zc[(long)c * Dd + n] = fmaf(cW1, v, fmaf(cb1, b1[n], qraw[(long)c * Dd + n] * sm[8768 + c]));
           });
  } else {
    const int id = bid - 320, b = id >> 1, m = 3 + (id & 1);
    const float* prev = ws + OFF_PREV + ((long)b * 6 + m) * Cc * Dd;
    const float* prek = ws + OFF_PREK + ((long)b * 6 + m) * Cc * Dd;
    const float* w1 = stateBase(ws, b, m) + (long)Dd * Dd;
    float av[16], ap[16];
#pragma unroll
    for (int c = 0; c < 16; c++) { av[c] = 0.f; ap[c] = 0.f; }
#pragma unroll
    for (int jj = 0; jj < 2; jj++) {
      const int h = tid + 512 * jj;
      const float w = w1[h];
#pragma unroll
      for (int c = 0; c < 16; c++) {
        av[c] = fmaf(silu(prev[(long)c * Dd + h]), w, av[c]);
        ap[c] = fmaf(silu(prek[(long)c * Dd + h]), w, ap[c]);
      }
    }
#pragma unroll
    for (int st = 1; st < 64; st <<= 1)
#pragma unroll
      for (int c = 0; c < 16; c++) {
        av[c] += __shfl_xor(av[c], st);
        ap[c] += __shfl_xor(ap[c], st);
      }
    if ((tid & 63) == 0) {
      const int w8 = tid >> 6;
#pragma unroll
      for (int c = 0; c < 16; c++) { sm[w8 * 32 + c] = av[c]; sm[w8 * 32 + 16 + c] = ap[c]; }
    }
    __syncthreads();
    if (tid == 0) {
      const float cW1 = scl[sidx(b, m, 0)], cb1 = scl[sidx(b, m, 1)];
      const float b10 = (stateBase(ws, b, m) + (long)Dd * Dd + 1024)[0];
      float* errP = ws + OFF_ERR + ((long)b * 6 + m) * Cc * Dd;
      for (int c = 0; c < 16; c++) {
        float sv = 0.f, sp = 0.f;
        for (int w8 = 0; w8 < 8; w8++) { sv += sm[w8 * 32 + c]; sp += sm[w8 * 32 + 16 + c]; }
        const float vh = fmaf(cW1, sv, cb1 * b10);
        const float pr = fmaf(cW1, sp, cb1 * b10);
        errP[(long)c * Dd] = (pr - vh) * 0.0625f;
      }
    }
  }
}

// S5: dl_dpre = (cW1 * err @ W1) * silu_grad(pre_k). grid 288x256. (round-1)
__global__ __launch_bounds__(256) void k_s5(float* ws) {
  __shared__ float errl[16384];
  const int tid = threadIdx.x, bid = blockIdx.x;
  const float* scl = ws + OFF_SCALE;
  if (bid < 256) {
    const int htile = bid & 15, mi = (bid >> 4) & 3, b = bid >> 6;
    const int m = BIGM[mi];
    const float* errP = ws + OFF_ERR + ((long)b * 6 + m) * Cc * Dd;
    for (int f = tid; f < 16384; f += 256) errl[f] = errP[f];
    __syncthreads();
    const int w = tid >> 6, l = tid & 63;
    const float cW1 = scl[sidx(b, m, 0)];
    const float* A = stateBase(ws, b, m) + (long)Dd * Dd;
    const float* prek = ws + OFF_PREK + ((long)b * 6 + m) * Cc * Dd;
    float* dlp = ws + OFF_DLP + ((long)b * 6 + m) * Cc * Dd;
    const int hb = htile * 64 + w * 16;
    const int myc = l & 15, myr = l >> 4;
#pragma unroll 1
    for (int rg = 0; rg < 4; rg++) {
      const int h0 = hb + rg * 4;
      float acc[16][4];
#pragma unroll
      for (int c = 0; c < 16; c++)
#pragma unroll
        for (int r = 0; r < 4; r++) acc[c][r] = 0.f;
      const float* A0 = A + (long)h0 * Dd + l;
#pragma unroll 1
      for (int j = 0; j < 16; j++) {
        const int k = 64 * j;
        const float a0 = A0[k], a1 = A0[k + Dd], a2 = A0[k + 2 * Dd], a3 = A0[k + 3 * Dd];
        const float* ep = errl + (k + l);
#pragma unroll
        for (int c = 0; c < 16; c++) {
          const float e = ep[c * 1024];
          acc[c][0] = fmaf(e, a0, acc[c][0]);
          acc[c][1] = fmaf(e, a1, acc[c][1]);
          acc[c][2] = fmaf(e, a2, acc[c][2]);
          acc[c][3] = fmaf(e, a3, acc[c][3]);
        }
      }
#pragma unroll
      for (int st = 1; st < 64; st <<= 1)
#pragma unroll
        for (int c = 0; c < 16; c++)
#pragma unroll
          for (int r = 0; r < 4; r++) acc[c][r] += __shfl_xor(acc[c][r], st);
      float val = 0.f;
#pragma unroll
      for (int c = 0; c < 16; c++)
#pragma unroll
        for (int r = 0; r < 4; r++) val = (c == myc && r == myr) ? acc[c][r] : val;
      const int h = h0 + myr;
      const float pre = prek[(long)myc * Dd + h];
      const float sg = sigm(pre);
      const float sgrad = sg * (1.f + pre * (1.f - sg));
      dlp[(long)myc * Dd + h] = cW1 * val * sgrad;
    }
  } else {
    const int e = bid - 256, sub = e & 3, bm = e >> 2, b = bm >> 1, m = 3 + (bm & 1);
    const float cW1 = scl[sidx(b, m, 0)];
    const float* errP = ws + OFF_ERR + ((long)b * 6 + m) * Cc * Dd;
    const float* prek = ws + OFF_PREK + ((long)b * 6 + m) * Cc * Dd;
    const float* w1 = stateBase(ws, b, m) + (long)Dd * Dd;
    float* dlp = ws + OFF_DLP + ((long)b * 6 + m) * Cc * Dd;
    for (int i = tid; i < 4096; i += 256) {
      const long idx = (long)sub * 4096 + i;
      const int c = (int)(idx >> 10), h = (int)(idx & 1023);
      const float e0 = errP[(long)c * Dd];
      const float pre = prek[idx];
      const float sg = sigm(pre);
      const float sgrad = sg * (1.f + pre * (1.f - sg));
      dlp[idx] = e0 * cW1 * w1[h] * sgrad;
    }
  }
}

// S6: fused gradient + update + sumsq. New tiling: thread owns 4 consecutive
// cols (float4 global r/w), broadcast factor staged as transposed LDS slice.
// grid 696x256: [0,384) W2T, [384,640) big W1T, [640,688) b1/b2, [688,696) ea W1.
__global__ __launch_bounds__(256) void k_s6(float* ws) {
  __shared__ float sm[64 * 20 + 8];
  float* slack = sm + 64 * 20;
  const int tid = threadIdx.x, bid = blockIdx.x;
  const float* scl = ws + OFF_SCALE;
  if (bid < 640) {
    const bool isW2 = bid < 384;
    int b, m, r0;
    const float* dsrc;  // per-col grads source (16 x 1024)
    float* W;
    int scaleIdx;
    if (isW2) {
      const int bm = bid >> 4;
      b = bm / 6; m = bm % 6; r0 = (bid & 15) * 64;
      dsrc = ws + OFF_DLP + ((long)b * 6 + m) * Cc * Dd;
      W = stateBase(ws, b, m);
      scaleIdx = sidx(b, m, 2);
      // stage knT[dd][c] = k_norm[c][r0+dd]
      const float* kraw = ws + OFF_KVQ + ((long)b * 3 + 0) * Cc * Dd;
      const float* rssq = ws + OFF_RSSQ + (long)b * 2 * Cc;
      for (int f = tid; f < 1024; f += 256) {
        const int dd = f & 63, c = f >> 6;
        const float invc = 1.f / fmaxf(sqrtf(rssq[c]), 1e-12f);
        sm[dd * 20 + c] = kraw[(long)c * Dd + r0 + dd] * invc;
      }
    } else {
      const int id = bid - 384, bm = id >> 4;
      b = bm >> 2; m = BIGM[bm & 3]; r0 = (id & 15) * 64;
      dsrc = ws + OFF_ERR + ((long)b * 6 + m) * Cc * Dd;
      W = stateBase(ws, b, m) + (long)Dd * Dd;
      scaleIdx = sidx(b, m, 0);
      const float* prek = ws + OFF_PREK + ((long)b * 6 + m) * Cc * Dd;
      for (int f = tid; f < 1024; f += 256) {
        const int dd = f & 63, c = f >> 6;
        sm[dd * 20 + c] = silu(prek[(long)c * Dd + r0 + dd]);
      }
    }
    float4 dl[16];
#pragma unroll
    for (int c = 0; c < 16; c++)
      dl[c] = *reinterpret_cast<const float4*>(&dsrc[(long)c * Dd + tid * 4]);
    __syncthreads();
    const float ea = ws[OFF_EA + b], aa = ws[OFF_EA + 4 + b];
    const float ac = aa * scl[scaleIdx];
    float ss = 0.f;
#pragma unroll 1
    for (int dd = 0; dd < 64; dd++) {
      const float4 k0 = *reinterpret_cast<const float4*>(&sm[dd * 20 + 0]);
      const float4 k1 = *reinterpret_cast<const float4*>(&sm[dd * 20 + 4]);
      const float4 k2 = *reinterpret_cast<const float4*>(&sm[dd * 20 + 8]);
      const float4 k3 = *reinterpret_cast<const float4*>(&sm[dd * 20 + 12]);
      float4* Wp = reinterpret_cast<float4*>(&W[(size_t)(r0 + dd) * Dd + tid * 4]);
      float4 w = *Wp;
      float gx = 0.f, gy = 0.f, gz = 0.f, gw = 0.f;
#pragma unroll
      for (int c = 0; c < 16; c++) {
        const float kn = fcomp(c < 4 ? k0 : (c < 8 ? k1 : (c < 12 ? k2 : k3)), c & 3);
        gx = fmaf(kn, dl[c].x, gx);
        gy = fmaf(kn, dl[c].y, gy);
        gz = fmaf(kn, dl[c].z, gz);
        gw = fmaf(kn, dl[c].w, gw);
      }
      w.x = fmaf(ac, w.x, -ea * gx);
      w.y = fmaf(ac, w.y, -ea * gy);
      w.z = fmaf(ac, w.z, -ea * gz);
      w.w = fmaf(ac, w.w, -ea * gw);
      *Wp = w;
      ss = fmaf(w.x, w.x, fmaf(w.y, w.y, fmaf(w.z, w.z, fmaf(w.w, w.w, ss))));
    }
    sumsqReduce(ss, slack, ws + OFF_SUMSQ + scaleIdx);
  } else {
    const int id = bid - 640;
    float ss = 0.f;
    if (id < 48) {
      const int b = id / 12, r = id % 12, m = r >> 1, which = r & 1;
      const float ea = ws[OFF_EA + b], aa = ws[OFF_EA + 4 + b];
      float* base = stateBase(ws, b, m);
      if (which == 0) {
        const int n = DOUTS[m];
        float* b1 = base + (long)Dd * Dd + (long)Dd * DOUTS[m];
        const float* errP = ws + OFF_ERR + ((long)b * 6 + m) * Cc * Dd;
        const float ac = aa * scl[sidx(b, m, 1)];
        for (int o = tid; o < n; o += 256) {
          float gsum = 0.f;
#pragma unroll
          for (int c = 0; c < 16; c++) gsum += errP[(long)c * Dd + o];
          const float nw = fmaf(ac, b1[o], -ea * gsum);
          b1[o] = nw;
          ss = fmaf(nw, nw, ss);
        }
        sumsqReduce(ss, slack, ws + OFF_SUMSQ + sidx(b, m, 1));
      } else {
        float* b2 = base + (long)Dd * Dd + (long)Dd * DOUTS[m] + 1024;
        const float* dlpP = ws + OFF_DLP + ((long)b * 6 + m) * Cc * Dd;
        const float ac = aa * scl[sidx(b, m, 3)];
        for (int hh = tid; hh < 1024; hh += 256) {
          float gsum = 0.f;
#pragma unroll
          for (int c = 0; c < 16; c++) gsum += dlpP[(long)c * Dd + hh];
          const float nw = fmaf(ac, b2[hh], -ea * gsum);
          b2[hh] = nw;
          ss = fmaf(nw, nw, ss);
        }
        sumsqReduce(ss, slack, ws + OFF_SUMSQ + sidx(b, m, 3));
      }
    } else {
      const int e2 = id - 48, b = e2 >> 1, m = 3 + (e2 & 1);
      const float ea = ws[OFF_EA + b], aa = ws[OFF_EA + 4 + b];
      float* W = stateBase(ws, b, m) + (long)Dd * Dd;
      const float* errP = ws + OFF_ERR + ((long)b * 6 + m) * Cc * Dd;
      const float* prek = ws + OFF_PREK + ((long)b * 6 + m) * Cc * Dd;
      const float ac = aa * scl[sidx(b, m, 0)];
      for (int h = tid; h < 1024; h += 256) {
        float gsum = 0.f;
#pragma unroll
        for (int c = 0; c < 16; c++)
          gsum = fmaf(errP[(long)c * Dd], silu(prek[(long)c * Dd + h]), gsum);
        const float nw = fmaf(ac, W[h], -ea * gsum);
        W[h] = nw;
        ss = fmaf(nw, nw, ss);
      }
      sumsqReduce(ss, slack, ws + OFF_SUMSQ + sidx(b, m, 0));
    }
  }
}

// ============================ epilogue ============================

__global__ __launch_bounds__(256) void k_ln(float* ws, const float* __restrict__ g,
                                            const float* __restrict__ bb) {
  __shared__ float sm[8];
  const long row = blockIdx.x;
  float* p = ws + OFF_Z + row * Dd;
  const int tid = threadIdx.x;
  float s = 0.f, s2 = 0.f;
  for (int j = tid; j < Dd; j += 256) {
    const float v = p[j];
    s += v;
    s2 = fmaf(v, v, s2);
  }
#pragma unroll
  for (int st = 32; st >= 1; st >>= 1) { s += __shfl_xor(s, st); s2 += __shfl_xor(s2, st); }
  if ((tid & 63) == 0) { sm[tid >> 6] = s; sm[4 + (tid >> 6)] = s2; }
  __syncthreads();
  const float S = sm[0] + sm[1] + sm[2] + sm[3];
  const float S2 = sm[4] + sm[5] + sm[6] + sm[7];
  const float mu = S * (1.f / 1024.f);
  const float var = S2 * (1.f / 1024.f) - mu * mu;
  const float inv = 1.f / sqrtf(var + 1e-5f);
  for (int j = tid; j < Dd; j += 256) {
    const float v = p[j];
    p[j] = fmaf((v - mu) * inv, g[j], bb[j]);
  }
}

}  // namespace

extern "C" void kernel_launch(void* const* d_in, const int* in_sizes, int n_in,
                              void* d_out, int out_size, void* d_ws, size_t ws_size,
                              hipStream_t stream) {
  (void)in_sizes; (void)n_in; (void)out_size;
  if (ws_size < (size_t)WS_FLOATS * sizeof(float)) return;
  float* ws = (float*)d_ws;
  InPtrs ip;
  for (int i = 0; i < 31; i++) ip.p[i] = (const float*)d_in[i];

  k_p0<<<256, 256, 0, stream>>>(ws, ip);
  k_p1<<<3072, 256, 0, stream>>>(ws, ip);
  k_gemm_big<<<8192, 512, 0, stream>>>((const float*)d_in[0], ws + OFF_INWT,
                                       (const float*)d_in[26], ws + OFF_Z);

  for (int t = 0; t < NCc; t++) {
    if (t) k_s0<<<1, 256, 0, stream>>>(ws, t);
    k_s1<<<320, 512, 0, stream>>>(ws, t);
    k_s2<<<200, 512, 0, stream>>>(ws, t);
    k_s3<<<448, 512, 0, stream>>>(ws);
    k_s4<<<328, 512, 0, stream>>>(ws, t);
    k_s5<<<288, 256, 0, stream>>>(ws);
    k_s6<<<696, 256, 0, stream>>>(ws);
  }

  k_ln<<<8192, 256, 0, stream>>>(ws, (const float*)d_in[29], (const float*)d_in[30]);
  k_gemm_big<<<8192, 512, 0, stream>>>(ws + OFF_Z, ws + OFF_OUTWT,
                                       (const float*)d_in[28], (float*)d_out);
}

// Round 5
// 33071.307 us; speedup vs baseline: 9.5475x; 9.5475x over previous
//
#include <hip/hip_runtime.h>
#include <math.h>

#define DI __device__ __forceinline__

namespace {

typedef unsigned short u16;
typedef unsigned int u32;
typedef __attribute__((ext_vector_type(8))) short bf8;   // 8 bf16
typedef __attribute__((ext_vector_type(4))) float f4;

DI f4 MFB(bf8 a, bf8 b, f4 c) { return __builtin_amdgcn_mfma_f32_16x16x32_bf16(a, b, c, 0, 0, 0); }

constexpr int DOUTS[6] = {1024, 1024, 1024, 1, 1, 1024};
constexpr int BIGM[4] = {0, 1, 2, 5};

// state blob per (b,m), fp32:
// big: [W2 1048576][W1 1048576][vec 3072]  small: [W2 1048576][vec 3072]
constexpr long SZ_BIGM = 2100224, SZ_SMALLM = 1051648;
constexpr long MODOFF[6] = {0, SZ_BIGM, 2 * SZ_BIGM, 3 * SZ_BIGM,
                            3 * SZ_BIGM + SZ_SMALLM, 3 * SZ_BIGM + 2 * SZ_SMALLM};
constexpr long BSTRIDE = 3 * SZ_BIGM + 2 * SZ_SMALLM + SZ_BIGM;

constexpr long OFF_Z     = 0;
constexpr long OFF_STATE = 8388608;
constexpr long OFF_SPRE5 = OFF_STATE + 4 * BSTRIDE;
constexpr long OFF_KVQ   = OFF_SPRE5 + 327680;
constexpr long OFF_SPREV = OFF_KVQ + 196608;
constexpr long OFF_PREK  = OFF_SPREV + 393216;
constexpr long OFF_SPREK = OFF_PREK + 393216;
constexpr long OFF_SPREO = OFF_SPREK + 393216;
constexpr long OFF_ERR   = OFF_SPREO + 65536;
constexpr long OFF_DLP   = OFF_ERR + 393216;
constexpr long OFF_RSSQ  = OFF_DLP + 393216;   // [b][2][16]
constexpr long OFF_EA    = OFF_RSSQ + 128;
constexpr long OFF_SCALE = OFF_EA + 8;
constexpr long OFF_SUMSQ = OFF_SCALE + 96;
constexpr long OFF_FLAG  = OFF_SUMSQ + 96;
constexpr long WS_FLOATS = OFF_FLAG + 8;       // ~52.96M floats = 211.9 MB

struct InPtrs { const float* p[31]; };

DI float* modBase(float* ws, int b, int m) {
  return ws + OFF_STATE + (long)b * BSTRIDE + MODOFF[m];
}
DI float* vecp(float* base, int m) { return base + ((m == 3 || m == 4) ? 1048576 : 2097152); }
DI int sidx(int b, int m, int p) { return ((b * 6 + m) << 2) + p; }
DI float maxnf(int m, int p) {
  switch (p) {
    case 0: return sqrtf((float)(1024 * DOUTS[m]));
    case 1: return sqrtf((float)DOUTS[m]);
    case 2: return 1024.0f;
    default: return 32.0f;
  }
}
DI float sigm(float x) { return 1.0f / (1.0f + expf(-x)); }
DI float silu(float x) { return x * sigm(x); }
DI u16 f2bf(float x) {
  u32 u = __float_as_uint(x);
  return (u16)((u + 0x7fffu + ((u >> 16) & 1u)) >> 16);
}

DI void sumsqReduce(float ss, float* slack, float* dst) {
#pragma unroll
  for (int st = 32; st >= 1; st >>= 1) ss += __shfl_xor(ss, st);
  const int tid = threadIdx.x;
  if ((tid & 63) == 0) slack[tid >> 6] = ss;
  __syncthreads();
  if (tid == 0) atomicAdd(dst, slack[0] + slack[1] + slack[2] + slack[3]);
  __syncthreads();
}

// 3-plane bf16 split: x = p0 + p1 + p2 with error <= ~2^-24 |x|.
DI void split3v(const float v[8], bf8& p0, bf8& p1, bf8& p2) {
#pragma unroll
  for (int i = 0; i < 8; i++) {
    const u32 u = __float_as_uint(v[i]);
    const float f0 = __uint_as_float(u & 0xffff0000u);
    const float r1 = v[i] - f0;
    const u32 u1 = __float_as_uint(r1);
    const float f1 = __uint_as_float(u1 & 0xffff0000u);
    const float r2 = r1 - f1;
    p0[i] = (short)(u >> 16);
    p1[i] = (short)(u1 >> 16);
    p2[i] = (short)f2bf(r2);
  }
}
DI void split3p(const float* p, bf8& p0, bf8& p1, bf8& p2) {
  const float4 a = *(const float4*)p, b = *(const float4*)(p + 4);
  const float v[8] = {a.x, a.y, a.z, a.w, b.x, b.y, b.z, b.w};
  split3v(v, p0, p1, p2);
}

// ============ layout probe: which (row,col) map does C/D use on this chip? ====
// D = A*B with A[m][0]=m+1, B[0][n]=128*(n+1) (exact bf16 ints).
// flag 0: row=(l>>4)*4+r, col=l&15  (m89-verified expectation). flag 1: transposed.
__global__ void k_probe(float* ws) {
  const int l = threadIdx.x, cl = l & 15, kq = l >> 4;
  bf8 af, bf_;
#pragma unroll
  for (int i = 0; i < 8; i++) { af[i] = 0; bf_[i] = 0; }
  if (kq == 0) {
    af[0] = (short)f2bf((float)(cl + 1));
    bf_[0] = (short)f2bf((float)(128 * (cl + 1)));
  }
  f4 d = MFB(af, bf_, f4{0.f, 0.f, 0.f, 0.f});
  bool m0 = true, m1 = true;
#pragma unroll
  for (int r = 0; r < 4; r++) {
    m0 = m0 && (d[r] == (float)((kq * 4 + r + 1) * 128 * (cl + 1)));
    m1 = m1 && (d[r] == (float)((cl + 1) * 128 * (kq * 4 + r + 1)));
  }
  const unsigned long long b0 = __ballot(m0), b1 = __ballot(m1);
  if (l == 0) ws[OFF_FLAG] = (b0 == ~0ull) ? 0.f : ((b1 == ~0ull) ? 1.f : 0.f);
}

// ============ bf16x3 MFMA cores (fp32-equivalent GEMM) =======================
// Y[c<16][n0+64) = sum_k X[c][k]*W[n][k]. 256 thr/4 waves; wave nt owns 16 cols,
// full K, no LDS/barriers. ef(c,n,val) called 4x/lane.
template <class EF>
DI void mc1(const float* __restrict__ X, const float* __restrict__ W,
            int n0, int flg, EF&& ef) {
  const int tid = threadIdx.x, nt = tid >> 6, l = tid & 63, cl = l & 15, kq = l >> 4;
  f4 acc = {0.f, 0.f, 0.f, 0.f};
  const float* Xr = X + (long)cl * 1024 + kq * 8;
  const float* Wr = W + (long)(n0 + nt * 16 + cl) * 1024 + kq * 8;
#pragma unroll 2
  for (int ch = 0; ch < 32; ch++) {
    bf8 x0, x1, x2, w0, w1, w2;
    split3p(Xr + ch * 32, x0, x1, x2);
    split3p(Wr + ch * 32, w0, w1, w2);
    acc = MFB(x2, w0, acc); acc = MFB(x1, w1, acc); acc = MFB(x0, w2, acc);
    acc = MFB(x1, w0, acc); acc = MFB(x0, w1, acc); acc = MFB(x0, w0, acc);
  }
#pragma unroll
  for (int r = 0; r < 4; r++) {
    const int c = flg ? cl : kq * 4 + r;
    const int n = n0 + nt * 16 + (flg ? kq * 4 + r : cl);
    ef(c, n, acc[r]);
  }
}

// dual-X: two X streams share one W pass (split W once, 12 MFMA).
template <class EF>
DI void mc2(const float* __restrict__ X1, const float* __restrict__ X2,
            const float* __restrict__ W, int n0, int flg, EF&& ef) {
  const int tid = threadIdx.x, nt = tid >> 6, l = tid & 63, cl = l & 15, kq = l >> 4;
  f4 a1 = {0.f, 0.f, 0.f, 0.f}, a2 = {0.f, 0.f, 0.f, 0.f};
  const float* X1r = X1 + (long)cl * 1024 + kq * 8;
  const float* X2r = X2 + (long)cl * 1024 + kq * 8;
  const float* Wr = W + (long)(n0 + nt * 16 + cl) * 1024 + kq * 8;
#pragma unroll 1
  for (int ch = 0; ch < 32; ch++) {
    bf8 w0, w1, w2, x0, x1, x2, y0, y1, y2;
    split3p(Wr + ch * 32, w0, w1, w2);
    split3p(X1r + ch * 32, x0, x1, x2);
    split3p(X2r + ch * 32, y0, y1, y2);
    a1 = MFB(x2, w0, a1); a1 = MFB(x1, w1, a1); a1 = MFB(x0, w2, a1);
    a1 = MFB(x1, w0, a1); a1 = MFB(x0, w1, a1); a1 = MFB(x0, w0, a1);
    a2 = MFB(y2, w0, a2); a2 = MFB(y1, w1, a2); a2 = MFB(y0, w2, a2);
    a2 = MFB(y1, w0, a2); a2 = MFB(y0, w1, a2); a2 = MFB(y0, w0, a2);
  }
#pragma unroll
  for (int r = 0; r < 4; r++) {
    const int c = flg ? cl : kq * 4 + r;
    const int n = n0 + nt * 16 + (flg ? kq * 4 + r : cl);
    ef(c, n, a1[r], a2[r]);
  }
}

// transposed-W core for s5: G[c][h] = sum_o E[c][o]*W1[o][h] (column access on W1).
template <class EF>
DI void mc1t(const float* __restrict__ E, const float* __restrict__ W1,
             int h0, int flg, EF&& ef) {
  const int tid = threadIdx.x, nt = tid >> 6, l = tid & 63, cl = l & 15, kq = l >> 4;
  f4 acc = {0.f, 0.f, 0.f, 0.f};
  const float* Er = E + (long)cl * 1024 + kq * 8;
  const float* Wc = W1 + (long)(kq * 8) * 1024 + h0 + nt * 16 + cl;
#pragma unroll 1
  for (int ch = 0; ch < 32; ch++) {
    bf8 x0, x1, x2, w0, w1, w2;
    split3p(Er + ch * 32, x0, x1, x2);
    float v[8];
#pragma unroll
    for (int i = 0; i < 8; i++) v[i] = Wc[(long)(ch * 32 + i) * 1024];
    split3v(v, w0, w1, w2);
    acc = MFB(x2, w0, acc); acc = MFB(x1, w1, acc); acc = MFB(x0, w2, acc);
    acc = MFB(x1, w0, acc); acc = MFB(x0, w1, acc); acc = MFB(x0, w0, acc);
  }
#pragma unroll
  for (int r = 0; r < 4; r++) {
    const int c = flg ? cl : kq * 4 + r;
    const int h = h0 + nt * 16 + (flg ? kq * 4 + r : cl);
    ef(c, h, acc[r]);
  }
}

// ============================ prologue ============================

__global__ __launch_bounds__(256) void k_p0(float* ws, InPtrs in) {
  const long i = threadIdx.x + (long)blockIdx.x * 256;
  if (i < 96) { ws[OFF_SCALE + i] = 1.f; return; }
  if (i < 192) { ws[OFF_SUMSQ + (i - 96)] = 0.f; return; }
  if (i < 320) { ws[OFF_RSSQ + (i - 192)] = 0.f; return; }
  const long j = i - 320;
  if (j < 24 * 2048) {
    const int bm = (int)(j >> 11), q = (int)(j & 2047);
    const int b = bm / 6, m = bm % 6;
    float* vc = vecp(modBase(ws, b, m), m);
    if (q < 1024) { if (q < DOUTS[m]) vc[q] = in.p[2 + 4 * m][q]; }
    else vc[1024 + (q - 1024)] = in.p[4 + 4 * m][q - 1024];
    return;
  }
  const long j2 = j - 49152;
  if (j2 < 8192) {
    const int e = (int)(j2 >> 10), b = e >> 1, m = 3 + (e & 1);
    const int h = (int)(j2 & 1023);
    vecp(modBase(ws, b, m), m)[2048 + h] = in.p[1 + 4 * m][h];
  }
}

__global__ __launch_bounds__(256) void k_pc(float* ws, InPtrs in) {
  const int bid = blockIdx.x, job = bid >> 9, sub = bid & 511;
  const long e0 = (long)sub * 2048 + threadIdx.x * 8;
  int m; bool w1;
  if (job < 6) { m = job; w1 = false; }
  else { m = BIGM[job - 6]; w1 = true; }
  const float* src = in.p[(w1 ? 1 : 3) + 4 * m];
  const float4 a = *(const float4*)(src + e0);
  const float4 b4 = *(const float4*)(src + e0 + 4);
#pragma unroll
  for (int q = 0; q < 4; q++) {
    float* dst = modBase(ws, q, m) + (w1 ? 1048576 : 0);
    *(float4*)(dst + e0) = a;
    *(float4*)(dst + e0 + 4) = b4;
  }
}

__global__ __launch_bounds__(256) void k_gbig(const float* __restrict__ X,
                                              const float* __restrict__ A,
                                              const float* __restrict__ bias,
                                              float* __restrict__ Y,
                                              const float* flagp) {
  const int bid = blockIdx.x, nb = bid & 15;
  const long rb = bid >> 4;
  const int flg = (int)flagp[0];
  const float* Xr = X + rb * 16 * 1024;
  float* Yr = Y + rb * 16 * 1024;
  mc1(Xr, A, nb * 64, flg, [&](int c, int n, float v) {
    Yr[(long)c * 1024 + n] = v + bias[n];
  });
}

// ============================ per-step ============================

__global__ __launch_bounds__(256) void k_s0(float* ws) {
  const int i = threadIdx.x;
  if (i < 96) {
    const float ssv = ws[OFF_SUMSQ + i];
    const int p = i & 3, m = (i >> 2) % 6;
    ws[OFF_SCALE + i] = fminf(maxnf(m, p) / (sqrtf(ssv) + 1e-8f), 1.0f);
    ws[OFF_SUMSQ + i] = 0.f;
  } else if (i < 224) {
    ws[OFF_RSSQ + (i - 96)] = 0.f;
  }
}

// S1: spre5 = silu(cW2*(z @ W2^T) + cb2*b2). grid 320.
__global__ __launch_bounds__(256) void k_s1(float* ws, int t) {
  const int bid = blockIdx.x, nb = bid & 15, m = (bid >> 4) % 5, b = bid / 80;
  const int flg = (int)ws[OFF_FLAG];
  const float* zc = ws + OFF_Z + ((long)b * 2048 + (long)t * 16) * 1024;
  float* base = modBase(ws, b, m);
  const float cW2 = ws[OFF_SCALE + sidx(b, m, 2)], cb2 = ws[OFF_SCALE + sidx(b, m, 3)];
  const float* b2v = vecp(base, m) + 1024;
  float* Y = ws + OFF_SPRE5 + ((long)b * 5 + m) * 16384;
  mc1(zc, base, nb * 64, flg, [&](int c, int n, float v) {
    Y[(long)c * 1024 + n] = silu(fmaf(cW2, v, cb2 * b2v[n]));
  });
}

// S2: kvq = cW1*(spre5 @ W1^T) + cb1*b1 + z ; rssq k,q ; eta/alpha heads. grid 200.
__global__ __launch_bounds__(256) void k_s2(float* ws, int t) {
  __shared__ float smr[16];
  const int tid = threadIdx.x, bid = blockIdx.x;
  if (bid < 192) {
    const int nb = bid & 15, m = (bid >> 4) % 3, b = bid / 48;
    const int flg = (int)ws[OFF_FLAG];
    if (tid < 16) smr[tid] = 0.f;
    __syncthreads();
    const float* spre = ws + OFF_SPRE5 + ((long)b * 5 + m) * 16384;
    float* base = modBase(ws, b, m);
    const float* zc = ws + OFF_Z + ((long)b * 2048 + (long)t * 16) * 1024;
    const float cW1 = ws[OFF_SCALE + sidx(b, m, 0)], cb1 = ws[OFF_SCALE + sidx(b, m, 1)];
    const float* b1v = vecp(base, m);
    float* out = ws + OFF_KVQ + ((long)b * 3 + m) * 16384;
    const bool sq = (m != 1);
    mc1(spre, base + 1048576, nb * 64, flg, [&](int c, int n, float v) {
      const float val = fmaf(cW1, v, fmaf(cb1, b1v[n], zc[(long)c * 1024 + n]));
      out[(long)c * 1024 + n] = val;
      if (sq) atomicAdd(&smr[c], val * val);
    });
    __syncthreads();
    if (sq && tid < 16)
      atomicAdd(ws + OFF_RSSQ + (long)b * 32 + (m == 0 ? 0 : 16) + tid, smr[tid]);
  } else {
    const int e = bid - 192, b = e >> 1, m = 3 + (e & 1);
    const float* spre = ws + OFF_SPRE5 + ((long)b * 5 + m) * 16384;
    float* base = modBase(ws, b, m);
    const float* w1 = vecp(base, m) + 2048;
    float av[16];
#pragma unroll
    for (int c = 0; c < 16; c++) av[c] = 0.f;
    for (int jj = 0; jj < 4; jj++) {
      const int h = tid + 256 * jj;
      const float w = w1[h];
#pragma unroll
      for (int c = 0; c < 16; c++) av[c] = fmaf(spre[c * 1024 + h], w, av[c]);
    }
#pragma unroll
    for (int st = 1; st < 64; st <<= 1)
#pragma unroll
      for (int c = 0; c < 16; c++) av[c] += __shfl_xor(av[c], st);
    __shared__ float sm2[64];
    if ((tid & 63) == 0) {
      const int w4 = tid >> 6;
#pragma unroll
      for (int c = 0; c < 16; c++) sm2[w4 * 16 + c] = av[c];
    }
    __syncthreads();
    if (tid == 0) {
      const float cW1 = ws[OFF_SCALE + sidx(b, m, 0)], cb1 = ws[OFF_SCALE + sidx(b, m, 1)];
      const float b10 = vecp(base, m)[0];
      float s = 0.f;
      for (int c = 0; c < 16; c++) {
        const float tot = sm2[c] + sm2[16 + c] + sm2[32 + c] + sm2[48 + c];
        s += sigm(fmaf(cW1, tot, cb1 * b10));
      }
      ws[OFF_EA + ((m == 3) ? 0 : 4) + b] = s * 0.0625f;
    }
  }
}

// S3: dual (v, k)@W2^T (inv folded in epilogue) -> sprev/prek/sprek ; q@memW2 -> spreo. grid 448.
__global__ __launch_bounds__(256) void k_s3(float* ws) {
  __shared__ float sminv[16];
  const int bid = blockIdx.x, tid = threadIdx.x;
  const int flg = (int)ws[OFF_FLAG];
  if (bid < 384) {
    const int nb = bid & 15, m = (bid >> 4) % 6, b = bid / 96;
    if (tid < 16)
      sminv[tid] = 1.f / fmaxf(sqrtf(ws[OFF_RSSQ + (long)b * 32 + tid]), 1e-12f);
    __syncthreads();
    const float* vX = ws + OFF_KVQ + ((long)b * 3 + 1) * 16384;
    const float* kX = ws + OFF_KVQ + ((long)b * 3 + 0) * 16384;
    float* base = modBase(ws, b, m);
    const float cW2 = ws[OFF_SCALE + sidx(b, m, 2)], cb2 = ws[OFF_SCALE + sidx(b, m, 3)];
    const float* b2v = vecp(base, m) + 1024;
    float* Ysv = ws + OFF_SPREV + ((long)b * 6 + m) * 16384;
    float* Yk = ws + OFF_PREK + ((long)b * 6 + m) * 16384;
    float* Ysk = ws + OFF_SPREK + ((long)b * 6 + m) * 16384;
    mc2(vX, kX, base, nb * 64, flg, [&](int c, int n, float v1, float v2) {
      const float bb = cb2 * b2v[n];
      Ysv[(long)c * 1024 + n] = silu(fmaf(cW2, v1, bb));
      const float pk = fmaf(cW2 * sminv[c], v2, bb);
      Yk[(long)c * 1024 + n] = pk;
      Ysk[(long)c * 1024 + n] = silu(pk);
    });
  } else {
    const int id = bid - 384, nb = id & 15, b = id >> 4;
    if (tid < 16)
      sminv[tid] = 1.f / fmaxf(sqrtf(ws[OFF_RSSQ + (long)b * 32 + 16 + tid]), 1e-12f);
    __syncthreads();
    const float* qX = ws + OFF_KVQ + ((long)b * 3 + 2) * 16384;
    float* base = modBase(ws, b, 5);
    const float cW2 = ws[OFF_SCALE + sidx(b, 5, 2)], cb2 = ws[OFF_SCALE + sidx(b, 5, 3)];
    const float* b2v = vecp(base, 5) + 1024;
    float* Y = ws + OFF_SPREO + (long)b * 16384;
    mc1(qX, base, nb * 64, flg, [&](int c, int n, float v) {
      Y[(long)c * 1024 + n] = silu(fmaf(cW2 * sminv[c], v, cb2 * b2v[n]));
    });
  }
}

// S4: dual (sprev,sprek)@W1^T -> err ; spreo@memW1 -> z ; eta/alpha heads. grid 328.
__global__ __launch_bounds__(256) void k_s4(float* ws, int t) {
  __shared__ float sminv[16];
  const int tid = threadIdx.x, bid = blockIdx.x;
  if (bid < 256) {
    const int nb = bid & 15, mi = (bid >> 4) & 3, b = bid >> 6;
    const int m = BIGM[mi];
    const int flg = (int)ws[OFF_FLAG];
    if (tid < 16)
      sminv[tid] = 1.f / fmaxf(sqrtf(ws[OFF_RSSQ + (long)b * 32 + tid]), 1e-12f);
    __syncthreads();
    const float* sprev = ws + OFF_SPREV + ((long)b * 6 + m) * 16384;
    const float* sprek = ws + OFF_SPREK + ((long)b * 6 + m) * 16384;
    float* base = modBase(ws, b, m);
    const float cW1 = ws[OFF_SCALE + sidx(b, m, 0)], cb1 = ws[OFF_SCALE + sidx(b, m, 1)];
    const float* b1v = vecp(base, m);
    const float* vraw = ws + OFF_KVQ + ((long)b * 3 + 1) * 16384;
    const float* kraw = ws + OFF_KVQ + ((long)b * 3 + 0) * 16384;
    float* errP = ws + OFF_ERR + ((long)b * 6 + m) * 16384;
    mc2(sprev, sprek, base + 1048576, nb * 64, flg, [&](int c, int n, float v1, float v2) {
      const float bbb = cb1 * b1v[n];
      const float vh = fmaf(cW1, v1, bbb + vraw[(long)c * 1024 + n]);
      const float pr = fmaf(cW1, v2, bbb + kraw[(long)c * 1024 + n] * sminv[c]);
      errP[(long)c * 1024 + n] = (pr - vh) * 0.0625f;
    });
  } else if (bid < 320) {
    const int id = bid - 256, nb = id & 15, b = id >> 4;
    const int flg = (int)ws[OFF_FLAG];
    if (tid < 16)
      sminv[tid] = 1.f / fmaxf(sqrtf(ws[OFF_RSSQ + (long)b * 32 + 16 + tid]), 1e-12f);
    __syncthreads();
    const float* spreo = ws + OFF_SPREO + (long)b * 16384;
    float* base = modBase(ws, b, 5);
    const float cW1 = ws[OFF_SCALE + sidx(b, 5, 0)], cb1 = ws[OFF_SCALE + sidx(b, 5, 1)];
    const float* b1v = vecp(base, 5);
    const float* qraw = ws + OFF_KVQ + ((long)b * 3 + 2) * 16384;
    float* zc = ws + OFF_Z + ((long)b * 2048 + (long)t * 16) * 1024;
    mc1(spreo, base + 1048576, nb * 64, flg, [&](int c, int n, float v) {
      zc[(long)c * 1024 + n] = fmaf(cW1, v, cb1 * b1v[n] + qraw[(long)c * 1024 + n] * sminv[c]);
    });
  } else {
    const int id = bid - 320, b = id >> 1, m = 3 + (id & 1);
    const float* sprev = ws + OFF_SPREV + ((long)b * 6 + m) * 16384;
    const float* sprek = ws + OFF_SPREK + ((long)b * 6 + m) * 16384;
    float* base = modBase(ws, b, m);
    const float* w1 = vecp(base, m) + 2048;
    float av[16], ap[16];
#pragma unroll
    for (int c = 0; c < 16; c++) { av[c] = 0.f; ap[c] = 0.f; }
    for (int jj = 0; jj < 4; jj++) {
      const int h = tid + 256 * jj;
      const float w = w1[h];
#pragma unroll
      for (int c = 0; c < 16; c++) {
        av[c] = fmaf(sprev[c * 1024 + h], w, av[c]);
        ap[c] = fmaf(sprek[c * 1024 + h], w, ap[c]);
      }
    }
#pragma unroll
    for (int st = 1; st < 64; st <<= 1)
#pragma unroll
      for (int c = 0; c < 16; c++) {
        av[c] += __shfl_xor(av[c], st);
        ap[c] += __shfl_xor(ap[c], st);
      }
    __shared__ float sm4[128];
    if ((tid & 63) == 0) {
      const int w4 = tid >> 6;
#pragma unroll
      for (int c = 0; c < 16; c++) { sm4[w4 * 32 + c] = av[c]; sm4[w4 * 32 + 16 + c] = ap[c]; }
    }
    __syncthreads();
    if (tid == 0) {
      const float cW1 = ws[OFF_SCALE + sidx(b, m, 0)], cb1 = ws[OFF_SCALE + sidx(b, m, 1)];
      const float b10 = vecp(base, m)[0];
      float* errP = ws + OFF_ERR + ((long)b * 6 + m) * 16384;
      for (int c = 0; c < 16; c++) {
        const float sv = sm4[c] + sm4[32 + c] + sm4[64 + c] + sm4[96 + c];
        const float sp = sm4[16 + c] + sm4[48 + c] + sm4[80 + c] + sm4[112 + c];
        errP[c * 1024] = (fmaf(cW1, sp, cb1 * b10) - fmaf(cW1, sv, cb1 * b10)) * 0.0625f;
      }
    }
  }
}

// S5: dlp = cW1*(err @ W1)*silu_grad(prek). grid 288.
__global__ __launch_bounds__(256) void k_s5(float* ws) {
  const int tid = threadIdx.x, bid = blockIdx.x;
  if (bid < 256) {
    const int hb = bid & 15, mi = (bid >> 4) & 3, b = bid >> 6;
    const int m = BIGM[mi];
    const int flg = (int)ws[OFF_FLAG];
    float* base = modBase(ws, b, m);
    const float* errP = ws + OFF_ERR + ((long)b * 6 + m) * 16384;
    const float cW1 = ws[OFF_SCALE + sidx(b, m, 0)];
    const float* prek = ws + OFF_PREK + ((long)b * 6 + m) * 16384;
    float* dlp = ws + OFF_DLP + ((long)b * 6 + m) * 16384;
    mc1t(errP, base + 1048576, hb * 64, flg, [&](int c, int h, float v) {
      const float pre = prek[(long)c * 1024 + h];
      const float sg = sigm(pre);
      dlp[(long)c * 1024 + h] = cW1 * v * (sg * (1.f + pre * (1.f - sg)));
    });
  } else {
    const int e = bid - 256, sub = e & 3, bm = e >> 2, b = bm >> 1, m = 3 + (bm & 1);
    const float cW1 = ws[OFF_SCALE + sidx(b, m, 0)];
    const float* errP = ws + OFF_ERR + ((long)b * 6 + m) * 16384;
    const float* prek = ws + OFF_PREK + ((long)b * 6 + m) * 16384;
    const float* w1 = vecp(modBase(ws, b, m), m) + 2048;
    float* dlp = ws + OFF_DLP + ((long)b * 6 + m) * 16384;
    for (int i = tid; i < 4096; i += 256) {
      const long idx = (long)sub * 4096 + i;
      const int c = (int)(idx >> 10), h = (int)(idx & 1023);
      const float pre = prek[idx];
      const float sg = sigm(pre);
      dlp[idx] = errP[c * 1024] * cW1 * w1[h] * (sg * (1.f + pre * (1.f - sg)));
    }
  }
}

// S6: fused grad + decay-update + sumsq, fp32 VALU (R1-proven). grid 216.
__global__ __launch_bounds__(256) void k_s6(float* ws) {
  __shared__ float sm[256 * 20 + 8];
  float* slack = sm + 5120;
  const int tid = threadIdx.x, bid = blockIdx.x;
  if (bid < 160) {
    const bool isW2 = bid < 96;
    int b, m, r0, scaleIdx;
    float* W;
    float4 fac[16];
    const float* tsrc;
    if (isW2) {
      const int bm = bid >> 2;
      b = bm / 6; m = bm % 6; r0 = (bid & 3) * 256;
      W = modBase(ws, b, m);
      scaleIdx = sidx(b, m, 2);
      tsrc = ws + OFF_DLP + ((long)b * 6 + m) * 16384;
      const float* kraw = ws + OFF_KVQ + ((long)b * 3) * 16384;
#pragma unroll
      for (int c = 0; c < 16; c++) {
        const float inv = 1.f / fmaxf(sqrtf(ws[OFF_RSSQ + (long)b * 32 + c]), 1e-12f);
        const float4 kk = *(const float4*)(kraw + (long)c * 1024 + tid * 4);
        fac[c].x = kk.x * inv; fac[c].y = kk.y * inv;
        fac[c].z = kk.z * inv; fac[c].w = kk.w * inv;
      }
    } else {
      const int id = bid - 96, bm = id >> 2;
      b = bm >> 2; m = BIGM[bm & 3]; r0 = (id & 3) * 256;
      W = modBase(ws, b, m) + 1048576;
      scaleIdx = sidx(b, m, 0);
      tsrc = ws + OFF_ERR + ((long)b * 6 + m) * 16384;
      const float* sprek = ws + OFF_SPREK + ((long)b * 6 + m) * 16384;
#pragma unroll
      for (int c = 0; c < 16; c++)
        fac[c] = *(const float4*)(sprek + (long)c * 1024 + tid * 4);
    }
    for (int f = tid; f < 4096; f += 256) {
      const int c = f >> 8, hh = f & 255;
      sm[hh * 20 + c] = tsrc[(long)c * 1024 + r0 + hh];
    }
    __syncthreads();
    const float ea = ws[OFF_EA + b], aa = ws[OFF_EA + 4 + b];
    const float ac = aa * ws[OFF_SCALE + scaleIdx];
    float ss = 0.f;
#pragma unroll 1
    for (int hh = 0; hh < 256; hh++) {
      const float4 q0 = *(const float4*)(sm + hh * 20);
      const float4 q1 = *(const float4*)(sm + hh * 20 + 4);
      const float4 q2 = *(const float4*)(sm + hh * 20 + 8);
      const float4 q3 = *(const float4*)(sm + hh * 20 + 12);
      float4 g = {0.f, 0.f, 0.f, 0.f};
#pragma unroll
      for (int c = 0; c < 16; c++) {
        const float4 qq = c < 4 ? q0 : (c < 8 ? q1 : (c < 12 ? q2 : q3));
        const float dv = (&qq.x)[c & 3];
        g.x = fmaf(dv, fac[c].x, g.x);
        g.y = fmaf(dv, fac[c].y, g.y);
        g.z = fmaf(dv, fac[c].z, g.z);
        g.w = fmaf(dv, fac[c].w, g.w);
      }
      float4* Wp = (float4*)(W + (size_t)(r0 + hh) * 1024 + tid * 4);
      float4 w = *Wp;
      w.x = fmaf(ac, w.x, -ea * g.x);
      w.y = fmaf(ac, w.y, -ea * g.y);
      w.z = fmaf(ac, w.z, -ea * g.z);
      w.w = fmaf(ac, w.w, -ea * g.w);
      *Wp = w;
      ss = fmaf(w.x, w.x, fmaf(w.y, w.y, fmaf(w.z, w.z, fmaf(w.w, w.w, ss))));
    }
    sumsqReduce(ss, slack, ws + OFF_SUMSQ + scaleIdx);
  } else if (bid < 208) {
    const int id = bid - 160;
    const int b = id / 12, r = id % 12, m = r >> 1, which = r & 1;
    const float ea = ws[OFF_EA + b], aa = ws[OFF_EA + 4 + b];
    float* vc = vecp(modBase(ws, b, m), m);
    float ss = 0.f;
    if (which == 0) {
      const int n = DOUTS[m];
      const float* errP = ws + OFF_ERR + ((long)b * 6 + m) * 16384;
      const float ac = aa * ws[OFF_SCALE + sidx(b, m, 1)];
      for (int o = tid; o < n; o += 256) {
        float gs = 0.f;
#pragma unroll
        for (int c = 0; c < 16; c++) gs += errP[c * 1024 + o];
        const float nw = fmaf(ac, vc[o], -ea * gs);
        vc[o] = nw;
        ss = fmaf(nw, nw, ss);
      }
      sumsqReduce(ss, slack, ws + OFF_SUMSQ + sidx(b, m, 1));
    } else {
      const float* dlpP = ws + OFF_DLP + ((long)b * 6 + m) * 16384;
      const float ac = aa * ws[OFF_SCALE + sidx(b, m, 3)];
      for (int h = tid; h < 1024; h += 256) {
        float gs = 0.f;
#pragma unroll
        for (int c = 0; c < 16; c++) gs += dlpP[c * 1024 + h];
        const float nw = fmaf(ac, vc[1024 + h], -ea * gs);
        vc[1024 + h] = nw;
        ss = fmaf(nw, nw, ss);
      }
      sumsqReduce(ss, slack, ws + OFF_SUMSQ + sidx(b, m, 3));
    }
  } else {
    const int e2 = bid - 208, b = e2 >> 1, m = 3 + (e2 & 1);
    const float ea = ws[OFF_EA + b], aa = ws[OFF_EA + 4 + b];
    float* vc = vecp(modBase(ws, b, m), m);
    const float* errP = ws + OFF_ERR + ((long)b * 6 + m) * 16384;
    const float* sprek = ws + OFF_SPREK + ((long)b * 6 + m) * 16384;
    const float ac = aa * ws[OFF_SCALE + sidx(b, m, 0)];
    float ss = 0.f;
    for (int h = tid; h < 1024; h += 256) {
      float gs = 0.f;
#pragma unroll
      for (int c = 0; c < 16; c++)
        gs = fmaf(errP[c * 1024], sprek[c * 1024 + h], gs);
      const float nw = fmaf(ac, vc[2048 + h], -ea * gs);
      vc[2048 + h] = nw;
      ss = fmaf(nw, nw, ss);
    }
    sumsqReduce(ss, slack, ws + OFF_SUMSQ + sidx(b, m, 0));
  }
}

// ============================ epilogue ============================

__global__ __launch_bounds__(256) void k_ln(float* ws, const float* __restrict__ g,
                                            const float* __restrict__ bb) {
  __shared__ float sm[8];
  float* p = ws + OFF_Z + (long)blockIdx.x * 1024;
  const int tid = threadIdx.x;
  float s = 0.f, s2 = 0.f;
  for (int j = tid; j < 1024; j += 256) {
    const float v = p[j];
    s += v;
    s2 = fmaf(v, v, s2);
  }
#pragma unroll
  for (int st = 32; st >= 1; st >>= 1) { s += __shfl_xor(s, st); s2 += __shfl_xor(s2, st); }
  if ((tid & 63) == 0) { sm[tid >> 6] = s; sm[4 + (tid >> 6)] = s2; }
  __syncthreads();
  const float S = sm[0] + sm[1] + sm[2] + sm[3];
  const float S2 = sm[4] + sm[5] + sm[6] + sm[7];
  const float mu = S * (1.f / 1024.f);
  const float var = S2 * (1.f / 1024.f) - mu * mu;
  const float inv = 1.f / sqrtf(var + 1e-5f);
  for (int j = tid; j < 1024; j += 256) {
    p[j] = fmaf((p[j] - mu) * inv, g[j], bb[j]);
  }
}

}  // namespace

extern "C" void kernel_launch(void* const* d_in, const int* in_sizes, int n_in,
                              void* d_out, int out_size, void* d_ws, size_t ws_size,
                              hipStream_t stream) {
  (void)in_sizes; (void)n_in; (void)out_size;
  if (ws_size < (size_t)WS_FLOATS * sizeof(float)) return;
  float* ws = (float*)d_ws;
  InPtrs ip;
  for (int i = 0; i < 31; i++) ip.p[i] = (const float*)d_in[i];

  k_probe<<<1, 64, 0, stream>>>(ws);
  k_p0<<<256, 256, 0, stream>>>(ws, ip);
  k_pc<<<5120, 256, 0, stream>>>(ws, ip);
  k_gbig<<<8192, 256, 0, stream>>>((const float*)d_in[0], (const float*)d_in[25],
                                   (const float*)d_in[26], ws + OFF_Z, ws + OFF_FLAG);

  for (int t = 0; t < 128; t++) {
    if (t) k_s0<<<1, 256, 0, stream>>>(ws);
    k_s1<<<320, 256, 0, stream>>>(ws, t);
    k_s2<<<200, 256, 0, stream>>>(ws, t);
    k_s3<<<448, 256, 0, stream>>>(ws);
    k_s4<<<328, 256, 0, stream>>>(ws, t);
    k_s5<<<288, 256, 0, stream>>>(ws);
    k_s6<<<216, 256, 0, stream>>>(ws);
  }

  k_ln<<<8192, 256, 0, stream>>>(ws, (const float*)d_in[29], (const float*)d_in[30]);
  k_gbig<<<8192, 256, 0, stream>>>(ws + OFF_Z, (const float*)d_in[27],
                                   (const float*)d_in[28], (float*)d_out, ws + OFF_FLAG);
}

// Round 6
// 25366.608 us; speedup vs baseline: 12.4474x; 1.3037x over previous
//
#include <hip/hip_runtime.h>
#include <math.h>

#define DI __device__ __forceinline__

namespace {

typedef unsigned short u16;
typedef unsigned int u32;
typedef __attribute__((ext_vector_type(8))) short bf8;   // 8 bf16
typedef __attribute__((ext_vector_type(4))) float f4;

DI f4 MFB(bf8 a, bf8 b, f4 c) { return __builtin_amdgcn_mfma_f32_16x16x32_bf16(a, b, c, 0, 0, 0); }

constexpr int DOUTS[6] = {1024, 1024, 1024, 1, 1, 1024};
constexpr int BIGM[4] = {0, 1, 2, 5};

// state blob per (b,m), fp32:
// big: [W2 1048576][W1 1048576][vec 3072]  small: [W2 1048576][vec 3072]
constexpr long SZ_BIGM = 2100224, SZ_SMALLM = 1051648;
constexpr long MODOFF[6] = {0, SZ_BIGM, 2 * SZ_BIGM, 3 * SZ_BIGM,
                            3 * SZ_BIGM + SZ_SMALLM, 3 * SZ_BIGM + 2 * SZ_SMALLM};
constexpr long BSTRIDE = 3 * SZ_BIGM + 2 * SZ_SMALLM + SZ_BIGM;

constexpr long OFF_Z     = 0;
constexpr long OFF_STATE = 8388608;
constexpr long OFF_SPRE5 = OFF_STATE + 4 * BSTRIDE;
constexpr long OFF_KVQ   = OFF_SPRE5 + 327680;
constexpr long OFF_SPREV = OFF_KVQ + 196608;
constexpr long OFF_PREK  = OFF_SPREV + 393216;
constexpr long OFF_SPREK = OFF_PREK + 393216;
constexpr long OFF_SPREO = OFF_SPREK + 393216;
constexpr long OFF_ERR   = OFF_SPREO + 65536;
constexpr long OFF_DLP   = OFF_ERR + 393216;
constexpr long OFF_RSSQ  = OFF_DLP + 393216;   // [b][2][16]
constexpr long OFF_EA    = OFF_RSSQ + 128;
constexpr long OFF_SCALE = OFF_EA + 8;
constexpr long OFF_SUMSQ = OFF_SCALE + 96;
constexpr long OFF_FLAG  = OFF_SUMSQ + 96;
constexpr long WS_FLOATS = OFF_FLAG + 8;       // ~52.96M floats = 211.9 MB

struct InPtrs { const float* p[31]; };

DI float* modBase(float* ws, int b, int m) {
  return ws + OFF_STATE + (long)b * BSTRIDE + MODOFF[m];
}
DI float* vecp(float* base, int m) { return base + ((m == 3 || m == 4) ? 1048576 : 2097152); }
DI int sidx(int b, int m, int p) { return ((b * 6 + m) << 2) + p; }
DI float maxnf(int m, int p) {
  switch (p) {
    case 0: return sqrtf((float)(1024 * DOUTS[m]));
    case 1: return sqrtf((float)DOUTS[m]);
    case 2: return 1024.0f;
    default: return 32.0f;
  }
}
DI float sigm(float x) { return 1.0f / (1.0f + expf(-x)); }
DI float silu(float x) { return x * sigm(x); }
DI u16 f2bf(float x) {
  u32 u = __float_as_uint(x);
  return (u16)((u + 0x7fffu + ((u >> 16) & 1u)) >> 16);
}

DI void sumsqReduce(float ss, float* slack, float* dst) {
#pragma unroll
  for (int st = 32; st >= 1; st >>= 1) ss += __shfl_xor(ss, st);
  const int tid = threadIdx.x;
  if ((tid & 63) == 0) slack[tid >> 6] = ss;
  __syncthreads();
  if (tid == 0) atomicAdd(dst, slack[0] + slack[1] + slack[2] + slack[3]);
  __syncthreads();
}

// 3-plane bf16 split: x = p0 + p1 + p2 with error <= ~2^-24 |x|.
DI void split3v(const float v[8], bf8& p0, bf8& p1, bf8& p2) {
#pragma unroll
  for (int i = 0; i < 8; i++) {
    const u32 u = __float_as_uint(v[i]);
    const float f0 = __uint_as_float(u & 0xffff0000u);
    const float r1 = v[i] - f0;
    const u32 u1 = __float_as_uint(r1);
    const float f1 = __uint_as_float(u1 & 0xffff0000u);
    const float r2 = r1 - f1;
    p0[i] = (short)(u >> 16);
    p1[i] = (short)(u1 >> 16);
    p2[i] = (short)f2bf(r2);
  }
}
DI void split3p(const float* p, bf8& p0, bf8& p1, bf8& p2) {
  const float4 a = *(const float4*)p, b = *(const float4*)(p + 4);
  const float v[8] = {a.x, a.y, a.z, a.w, b.x, b.y, b.z, b.w};
  split3v(v, p0, p1, p2);
}

// ============ layout probe (unchanged, R5-verified) ============
__global__ void k_probe(float* ws) {
  const int l = threadIdx.x, cl = l & 15, kq = l >> 4;
  bf8 af, bf_;
#pragma unroll
  for (int i = 0; i < 8; i++) { af[i] = 0; bf_[i] = 0; }
  if (kq == 0) {
    af[0] = (short)f2bf((float)(cl + 1));
    bf_[0] = (short)f2bf((float)(128 * (cl + 1)));
  }
  f4 d = MFB(af, bf_, f4{0.f, 0.f, 0.f, 0.f});
  bool m0 = true, m1 = true;
#pragma unroll
  for (int r = 0; r < 4; r++) {
    m0 = m0 && (d[r] == (float)((kq * 4 + r + 1) * 128 * (cl + 1)));
    m1 = m1 && (d[r] == (float)((cl + 1) * 128 * (kq * 4 + r + 1)));
  }
  const unsigned long long b0 = __ballot(m0), b1 = __ballot(m1);
  if (l == 0) ws[OFF_FLAG] = (b0 == ~0ull) ? 0.f : ((b1 == ~0ull) ? 1.f : 0.f);
}

// ============ K-split bf16x3 MFMA cores ============
// One 16x16 output tile per block; 4 waves split K (256 each); LDS combine.
// Y[c<16][n0..n0+16) = sum_k X[c][k]*W[n][k].  ef(c,n,val) once per thread.
template <class EF>
DI void mcK1(float* sm, const float* __restrict__ X, const float* __restrict__ W,
             int n0, int flg, EF&& ef) {
  const int tid = threadIdx.x, g = tid >> 6, l = tid & 63, cl = l & 15, kq = l >> 4;
  f4 acc = {0.f, 0.f, 0.f, 0.f};
  const float* Xr = X + (long)cl * 1024 + g * 256 + kq * 8;
  const float* Wr = W + (long)(n0 + cl) * 1024 + g * 256 + kq * 8;
#pragma unroll 2
  for (int ch = 0; ch < 8; ch++) {
    bf8 x0, x1, x2, w0, w1, w2;
    split3p(Xr + ch * 32, x0, x1, x2);
    split3p(Wr + ch * 32, w0, w1, w2);
    acc = MFB(x2, w0, acc); acc = MFB(x1, w1, acc); acc = MFB(x0, w2, acc);
    acc = MFB(x1, w0, acc); acc = MFB(x0, w1, acc); acc = MFB(x0, w0, acc);
  }
  *(f4*)(sm + g * 256 + l * 4) = acc;
  __syncthreads();
  const int le = tid >> 2, re = tid & 3;
  const float v = sm[le * 4 + re] + sm[256 + le * 4 + re] +
                  sm[512 + le * 4 + re] + sm[768 + le * 4 + re];
  const int ccl = le & 15, ckq = le >> 4;
  const int c = flg ? ccl : ckq * 4 + re;
  const int n = n0 + (flg ? ckq * 4 + re : ccl);
  ef(c, n, v);
}

// dual-X: two X streams share one W split. LDS needs 2048 floats.
template <class EF>
DI void mcK2(float* sm, const float* __restrict__ X1, const float* __restrict__ X2,
             const float* __restrict__ W, int n0, int flg, EF&& ef) {
  const int tid = threadIdx.x, g = tid >> 6, l = tid & 63, cl = l & 15, kq = l >> 4;
  f4 a1 = {0.f, 0.f, 0.f, 0.f}, a2 = {0.f, 0.f, 0.f, 0.f};
  const float* X1r = X1 + (long)cl * 1024 + g * 256 + kq * 8;
  const float* X2r = X2 + (long)cl * 1024 + g * 256 + kq * 8;
  const float* Wr = W + (long)(n0 + cl) * 1024 + g * 256 + kq * 8;
#pragma unroll 2
  for (int ch = 0; ch < 8; ch++) {
    bf8 w0, w1, w2, x0, x1, x2, y0, y1, y2;
    split3p(Wr + ch * 32, w0, w1, w2);
    split3p(X1r + ch * 32, x0, x1, x2);
    split3p(X2r + ch * 32, y0, y1, y2);
    a1 = MFB(x2, w0, a1); a1 = MFB(x1, w1, a1); a1 = MFB(x0, w2, a1);
    a1 = MFB(x1, w0, a1); a1 = MFB(x0, w1, a1); a1 = MFB(x0, w0, a1);
    a2 = MFB(y2, w0, a2); a2 = MFB(y1, w1, a2); a2 = MFB(y0, w2, a2);
    a2 = MFB(y1, w0, a2); a2 = MFB(y0, w1, a2); a2 = MFB(y0, w0, a2);
  }
  *(f4*)(sm + g * 256 + l * 4) = a1;
  *(f4*)(sm + 1024 + g * 256 + l * 4) = a2;
  __syncthreads();
  const int le = tid >> 2, re = tid & 3;
  const float v1 = sm[le * 4 + re] + sm[256 + le * 4 + re] +
                   sm[512 + le * 4 + re] + sm[768 + le * 4 + re];
  const float v2 = sm[1024 + le * 4 + re] + sm[1280 + le * 4 + re] +
                   sm[1536 + le * 4 + re] + sm[1792 + le * 4 + re];
  const int ccl = le & 15, ckq = le >> 4;
  const int c = flg ? ccl : ckq * 4 + re;
  const int n = n0 + (flg ? ckq * 4 + re : ccl);
  ef(c, n, v1, v2);
}

// transposed-W core (s5): G[c][h] = sum_o E[c][o]*W1[o][h], column access on W1.
template <class EF>
DI void mcK1t(float* sm, const float* __restrict__ E, const float* __restrict__ W1,
              int h0, int flg, EF&& ef) {
  const int tid = threadIdx.x, g = tid >> 6, l = tid & 63, cl = l & 15, kq = l >> 4;
  f4 acc = {0.f, 0.f, 0.f, 0.f};
  const float* Er = E + (long)cl * 1024 + g * 256 + kq * 8;
  const float* Wc = W1 + (long)(g * 256 + kq * 8) * 1024 + h0 + cl;
#pragma unroll 2
  for (int ch = 0; ch < 8; ch++) {
    bf8 x0, x1, x2, w0, w1, w2;
    split3p(Er + ch * 32, x0, x1, x2);
    float v[8];
#pragma unroll
    for (int i = 0; i < 8; i++) v[i] = Wc[(long)(ch * 32 + i) * 1024];
    split3v(v, w0, w1, w2);
    acc = MFB(x2, w0, acc); acc = MFB(x1, w1, acc); acc = MFB(x0, w2, acc);
    acc = MFB(x1, w0, acc); acc = MFB(x0, w1, acc); acc = MFB(x0, w0, acc);
  }
  *(f4*)(sm + g * 256 + l * 4) = acc;
  __syncthreads();
  const int le = tid >> 2, re = tid & 3;
  const float v = sm[le * 4 + re] + sm[256 + le * 4 + re] +
                  sm[512 + le * 4 + re] + sm[768 + le * 4 + re];
  const int ccl = le & 15, ckq = le >> 4;
  const int c = flg ? ccl : ckq * 4 + re;
  const int h = h0 + (flg ? ckq * 4 + re : ccl);
  ef(c, h, v);
}

// ============================ prologue ============================

__global__ __launch_bounds__(256) void k_p0(float* ws, InPtrs in) {
  const long i = threadIdx.x + (long)blockIdx.x * 256;
  if (i < 96) { ws[OFF_SCALE + i] = 1.f; return; }
  if (i < 192) { ws[OFF_SUMSQ + (i - 96)] = 0.f; return; }
  if (i < 320) { ws[OFF_RSSQ + (i - 192)] = 0.f; return; }
  const long j = i - 320;
  if (j < 24 * 2048) {
    const int bm = (int)(j >> 11), q = (int)(j & 2047);
    const int b = bm / 6, m = bm % 6;
    float* vc = vecp(modBase(ws, b, m), m);
    if (q < 1024) { if (q < DOUTS[m]) vc[q] = in.p[2 + 4 * m][q]; }
    else vc[1024 + (q - 1024)] = in.p[4 + 4 * m][q - 1024];
    return;
  }
  const long j2 = j - 49152;
  if (j2 < 8192) {
    const int e = (int)(j2 >> 10), b = e >> 1, m = 3 + (e & 1);
    const int h = (int)(j2 & 1023);
    vecp(modBase(ws, b, m), m)[2048 + h] = in.p[1 + 4 * m][h];
  }
}

__global__ __launch_bounds__(256) void k_pc(float* ws, InPtrs in) {
  const int bid = blockIdx.x, job = bid >> 9, sub = bid & 511;
  const long e0 = (long)sub * 2048 + threadIdx.x * 8;
  int m; bool w1;
  if (job < 6) { m = job; w1 = false; }
  else { m = BIGM[job - 6]; w1 = true; }
  const float* src = in.p[(w1 ? 1 : 3) + 4 * m];
  const float4 a = *(const float4*)(src + e0);
  const float4 b4 = *(const float4*)(src + e0 + 4);
#pragma unroll
  for (int q = 0; q < 4; q++) {
    float* dst = modBase(ws, q, m) + (w1 ? 1048576 : 0);
    *(float4*)(dst + e0) = a;
    *(float4*)(dst + e0 + 4) = b4;
  }
}

__global__ __launch_bounds__(256) void k_gbig(const float* __restrict__ X,
                                              const float* __restrict__ A,
                                              const float* __restrict__ bias,
                                              float* __restrict__ Y,
                                              const float* flagp) {
  __shared__ float sm[1024];
  const int bid = blockIdx.x, nb = bid & 63;
  const long rb = bid >> 6;
  const int flg = (int)flagp[0];
  const float* Xr = X + rb * 16 * 1024;
  float* Yr = Y + rb * 16 * 1024;
  mcK1(sm, Xr, A, nb * 16, flg, [&](int c, int n, float v) {
    Yr[(long)c * 1024 + n] = v + bias[n];
  });
}

// ============================ per-step ============================

__global__ __launch_bounds__(256) void k_s0(float* ws) {
  const int i = threadIdx.x;
  if (i < 96) {
    const float ssv = ws[OFF_SUMSQ + i];
    const int p = i & 3, m = (i >> 2) % 6;
    ws[OFF_SCALE + i] = fminf(maxnf(m, p) / (sqrtf(ssv) + 1e-8f), 1.0f);
    ws[OFF_SUMSQ + i] = 0.f;
  } else if (i < 224) {
    ws[OFF_RSSQ + (i - 96)] = 0.f;
  }
}

// S1: spre5 = silu(cW2*(z @ W2^T) + cb2*b2). grid 1280.
__global__ __launch_bounds__(256) void k_s1(float* ws, int t) {
  __shared__ float sm[1024];
  const int bid = blockIdx.x, n0 = (bid & 63) * 16, m = (bid >> 6) % 5, b = bid / 320;
  const int flg = (int)ws[OFF_FLAG];
  const float* zc = ws + OFF_Z + ((long)b * 2048 + (long)t * 16) * 1024;
  float* base = modBase(ws, b, m);
  const float cW2 = ws[OFF_SCALE + sidx(b, m, 2)], cb2 = ws[OFF_SCALE + sidx(b, m, 3)];
  const float* b2v = vecp(base, m) + 1024;
  float* Y = ws + OFF_SPRE5 + ((long)b * 5 + m) * 16384;
  mcK1(sm, zc, base, n0, flg, [&](int c, int n, float v) {
    Y[(long)c * 1024 + n] = silu(fmaf(cW2, v, cb2 * b2v[n]));
  });
}

// S2: kvq = cW1*(spre5 @ W1^T) + cb1*b1 + z ; rssq k,q ; eta/alpha heads. grid 776.
__global__ __launch_bounds__(256) void k_s2(float* ws, int t) {
  __shared__ float sm[1024 + 16 + 64];
  float* smr = sm + 1024;
  float* sm2 = sm + 1040;
  const int tid = threadIdx.x, bid = blockIdx.x;
  if (bid < 768) {
    const int n0 = (bid & 63) * 16, m = (bid >> 6) % 3, b = bid / 192;
    const int flg = (int)ws[OFF_FLAG];
    if (tid < 16) smr[tid] = 0.f;
    const float* spre = ws + OFF_SPRE5 + ((long)b * 5 + m) * 16384;
    float* base = modBase(ws, b, m);
    const float* zc = ws + OFF_Z + ((long)b * 2048 + (long)t * 16) * 1024;
    const float cW1 = ws[OFF_SCALE + sidx(b, m, 0)], cb1 = ws[OFF_SCALE + sidx(b, m, 1)];
    const float* b1v = vecp(base, m);
    float* out = ws + OFF_KVQ + ((long)b * 3 + m) * 16384;
    const bool sq = (m != 1);
    mcK1(sm, spre, base + 1048576, n0, flg, [&](int c, int n, float v) {
      const float val = fmaf(cW1, v, fmaf(cb1, b1v[n], zc[(long)c * 1024 + n]));
      out[(long)c * 1024 + n] = val;
      if (sq) atomicAdd(&smr[c], val * val);
    });
    __syncthreads();
    if (sq && tid < 16)
      atomicAdd(ws + OFF_RSSQ + (long)b * 32 + (m == 0 ? 0 : 16) + tid, smr[tid]);
  } else {
    const int e = bid - 768, b = e >> 1, m = 3 + (e & 1);
    const float* spre = ws + OFF_SPRE5 + ((long)b * 5 + m) * 16384;
    float* base = modBase(ws, b, m);
    const float* w1 = vecp(base, m) + 2048;
    float av[16];
#pragma unroll
    for (int c = 0; c < 16; c++) av[c] = 0.f;
    for (int jj = 0; jj < 4; jj++) {
      const int h = tid + 256 * jj;
      const float w = w1[h];
#pragma unroll
      for (int c = 0; c < 16; c++) av[c] = fmaf(spre[c * 1024 + h], w, av[c]);
    }
#pragma unroll
    for (int st = 1; st < 64; st <<= 1)
#pragma unroll
      for (int c = 0; c < 16; c++) av[c] += __shfl_xor(av[c], st);
    if ((tid & 63) == 0) {
      const int w4 = tid >> 6;
#pragma unroll
      for (int c = 0; c < 16; c++) sm2[w4 * 16 + c] = av[c];
    }
    __syncthreads();
    if (tid == 0) {
      const float cW1 = ws[OFF_SCALE + sidx(b, m, 0)], cb1 = ws[OFF_SCALE + sidx(b, m, 1)];
      const float b10 = vecp(base, m)[0];
      float s = 0.f;
      for (int c = 0; c < 16; c++) {
        const float tot = sm2[c] + sm2[16 + c] + sm2[32 + c] + sm2[48 + c];
        s += sigm(fmaf(cW1, tot, cb1 * b10));
      }
      ws[OFF_EA + ((m == 3) ? 0 : 4) + b] = s * 0.0625f;
    }
  }
}

// S3: dual (v,k)@W2^T -> sprev/prek/sprek ; q@memW2 -> spreo. grid 1792.
__global__ __launch_bounds__(256) void k_s3(float* ws) {
  __shared__ float sm[2048 + 16];
  float* sminv = sm + 2048;
  const int bid = blockIdx.x, tid = threadIdx.x;
  const int flg = (int)ws[OFF_FLAG];
  if (bid < 1536) {
    const int n0 = (bid & 63) * 16, m = (bid >> 6) % 6, b = bid / 384;
    if (tid < 16)
      sminv[tid] = 1.f / fmaxf(sqrtf(ws[OFF_RSSQ + (long)b * 32 + tid]), 1e-12f);
    const float* vX = ws + OFF_KVQ + ((long)b * 3 + 1) * 16384;
    const float* kX = ws + OFF_KVQ + ((long)b * 3 + 0) * 16384;
    float* base = modBase(ws, b, m);
    const float cW2 = ws[OFF_SCALE + sidx(b, m, 2)], cb2 = ws[OFF_SCALE + sidx(b, m, 3)];
    const float* b2v = vecp(base, m) + 1024;
    float* Ysv = ws + OFF_SPREV + ((long)b * 6 + m) * 16384;
    float* Yk = ws + OFF_PREK + ((long)b * 6 + m) * 16384;
    float* Ysk = ws + OFF_SPREK + ((long)b * 6 + m) * 16384;
    mcK2(sm, vX, kX, base, n0, flg, [&](int c, int n, float v1, float v2) {
      const float bb = cb2 * b2v[n];
      Ysv[(long)c * 1024 + n] = silu(fmaf(cW2, v1, bb));
      const float pk = fmaf(cW2 * sminv[c], v2, bb);
      Yk[(long)c * 1024 + n] = pk;
      Ysk[(long)c * 1024 + n] = silu(pk);
    });
  } else {
    const int id = bid - 1536, n0 = (id & 63) * 16, b = id >> 6;
    if (tid < 16)
      sminv[tid] = 1.f / fmaxf(sqrtf(ws[OFF_RSSQ + (long)b * 32 + 16 + tid]), 1e-12f);
    const float* qX = ws + OFF_KVQ + ((long)b * 3 + 2) * 16384;
    float* base = modBase(ws, b, 5);
    const float cW2 = ws[OFF_SCALE + sidx(b, 5, 2)], cb2 = ws[OFF_SCALE + sidx(b, 5, 3)];
    const float* b2v = vecp(base, 5) + 1024;
    float* Y = ws + OFF_SPREO + (long)b * 16384;
    mcK1(sm, qX, base, n0, flg, [&](int c, int n, float v) {
      Y[(long)c * 1024 + n] = silu(fmaf(cW2 * sminv[c], v, cb2 * b2v[n]));
    });
  }
}

// S4: dual (sprev,sprek)@W1^T -> err ; spreo@memW1 -> z ; eta/alpha heads. grid 1288.
__global__ __launch_bounds__(256) void k_s4(float* ws, int t) {
  __shared__ float sm[2048 + 16 + 128];
  float* sminv = sm + 2048;
  float* sm4 = sm + 2064;
  const int tid = threadIdx.x, bid = blockIdx.x;
  if (bid < 1024) {
    const int n0 = (bid & 63) * 16, mi = (bid >> 6) & 3, b = bid >> 8;
    const int m = BIGM[mi];
    const int flg = (int)ws[OFF_FLAG];
    if (tid < 16)
      sminv[tid] = 1.f / fmaxf(sqrtf(ws[OFF_RSSQ + (long)b * 32 + tid]), 1e-12f);
    const float* sprev = ws + OFF_SPREV + ((long)b * 6 + m) * 16384;
    const float* sprek = ws + OFF_SPREK + ((long)b * 6 + m) * 16384;
    float* base = modBase(ws, b, m);
    const float cW1 = ws[OFF_SCALE + sidx(b, m, 0)], cb1 = ws[OFF_SCALE + sidx(b, m, 1)];
    const float* b1v = vecp(base, m);
    const float* vraw = ws + OFF_KVQ + ((long)b * 3 + 1) * 16384;
    const float* kraw = ws + OFF_KVQ + ((long)b * 3 + 0) * 16384;
    float* errP = ws + OFF_ERR + ((long)b * 6 + m) * 16384;
    mcK2(sm, sprev, sprek, base + 1048576, n0, flg, [&](int c, int n, float v1, float v2) {
      const float bbb = cb1 * b1v[n];
      const float vh = fmaf(cW1, v1, bbb + vraw[(long)c * 1024 + n]);
      const float pr = fmaf(cW1, v2, bbb + kraw[(long)c * 1024 + n] * sminv[c]);
      errP[(long)c * 1024 + n] = (pr - vh) * 0.0625f;
    });
  } else if (bid < 1280) {
    const int id = bid - 1024, n0 = (id & 63) * 16, b = id >> 6;
    const int flg = (int)ws[OFF_FLAG];
    if (tid < 16)
      sminv[tid] = 1.f / fmaxf(sqrtf(ws[OFF_RSSQ + (long)b * 32 + 16 + tid]), 1e-12f);
    const float* spreo = ws + OFF_SPREO + (long)b * 16384;
    float* base = modBase(ws, b, 5);
    const float cW1 = ws[OFF_SCALE + sidx(b, 5, 0)], cb1 = ws[OFF_SCALE + sidx(b, 5, 1)];
    const float* b1v = vecp(base, 5);
    const float* qraw = ws + OFF_KVQ + ((long)b * 3 + 2) * 16384;
    float* zc = ws + OFF_Z + ((long)b * 2048 + (long)t * 16) * 1024;
    mcK1(sm, spreo, base + 1048576, n0, flg, [&](int c, int n, float v) {
      zc[(long)c * 1024 + n] = fmaf(cW1, v, cb1 * b1v[n] + qraw[(long)c * 1024 + n] * sminv[c]);
    });
  } else {
    const int id = bid - 1280, b = id >> 1, m = 3 + (id & 1);
    const float* sprev = ws + OFF_SPREV + ((long)b * 6 + m) * 16384;
    const float* sprek = ws + OFF_SPREK + ((long)b * 6 + m) * 16384;
    float* base = modBase(ws, b, m);
    const float* w1 = vecp(base, m) + 2048;
    float av[16], ap[16];
#pragma unroll
    for (int c = 0; c < 16; c++) { av[c] = 0.f; ap[c] = 0.f; }
    for (int jj = 0; jj < 4; jj++) {
      const int h = tid + 256 * jj;
      const float w = w1[h];
#pragma unroll
      for (int c = 0; c < 16; c++) {
        av[c] = fmaf(sprev[c * 1024 + h], w, av[c]);
        ap[c] = fmaf(sprek[c * 1024 + h], w, ap[c]);
      }
    }
#pragma unroll
    for (int st = 1; st < 64; st <<= 1)
#pragma unroll
      for (int c = 0; c < 16; c++) {
        av[c] += __shfl_xor(av[c], st);
        ap[c] += __shfl_xor(ap[c], st);
      }
    if ((tid & 63) == 0) {
      const int w4 = tid >> 6;
#pragma unroll
      for (int c = 0; c < 16; c++) { sm4[w4 * 32 + c] = av[c]; sm4[w4 * 32 + 16 + c] = ap[c]; }
    }
    __syncthreads();
    if (tid == 0) {
      const float cW1 = ws[OFF_SCALE + sidx(b, m, 0)], cb1 = ws[OFF_SCALE + sidx(b, m, 1)];
      const float b10 = vecp(base, m)[0];
      float* errP = ws + OFF_ERR + ((long)b * 6 + m) * 16384;
      for (int c = 0; c < 16; c++) {
        const float sv = sm4[c] + sm4[32 + c] + sm4[64 + c] + sm4[96 + c];
        const float sp = sm4[16 + c] + sm4[48 + c] + sm4[80 + c] + sm4[112 + c];
        errP[c * 1024] = (fmaf(cW1, sp, cb1 * b10) - fmaf(cW1, sv, cb1 * b10)) * 0.0625f;
      }
    }
  }
}

// S5: dlp = cW1*(err @ W1)*silu_grad(prek). grid 1056.
__global__ __launch_bounds__(256) void k_s5(float* ws) {
  __shared__ float sm[1024];
  const int tid = threadIdx.x, bid = blockIdx.x;
  if (bid < 1024) {
    const int h0 = (bid & 63) * 16, mi = (bid >> 6) & 3, b = bid >> 8;
    const int m = BIGM[mi];
    const int flg = (int)ws[OFF_FLAG];
    float* base = modBase(ws, b, m);
    const float* errP = ws + OFF_ERR + ((long)b * 6 + m) * 16384;
    const float cW1 = ws[OFF_SCALE + sidx(b, m, 0)];
    const float* prek = ws + OFF_PREK + ((long)b * 6 + m) * 16384;
    float* dlp = ws + OFF_DLP + ((long)b * 6 + m) * 16384;
    mcK1t(sm, errP, base + 1048576, h0, flg, [&](int c, int h, float v) {
      const float pre = prek[(long)c * 1024 + h];
      const float sg = sigm(pre);
      dlp[(long)c * 1024 + h] = cW1 * v * (sg * (1.f + pre * (1.f - sg)));
    });
  } else {
    const int e = bid - 1024, sub = e & 3, bm = e >> 2, b = bm >> 1, m = 3 + (bm & 1);
    const float cW1 = ws[OFF_SCALE + sidx(b, m, 0)];
    const float* errP = ws + OFF_ERR + ((long)b * 6 + m) * 16384;
    const float* prek = ws + OFF_PREK + ((long)b * 6 + m) * 16384;
    const float* w1 = vecp(modBase(ws, b, m), m) + 2048;
    float* dlp = ws + OFF_DLP + ((long)b * 6 + m) * 16384;
    for (int i = tid; i < 4096; i += 256) {
      const long idx = (long)sub * 4096 + i;
      const int c = (int)(idx >> 10), h = (int)(idx & 1023);
      const float pre = prek[idx];
      const float sg = sigm(pre);
      dlp[idx] = errP[c * 1024] * cW1 * w1[h] * (sg * (1.f + pre * (1.f - sg)));
    }
  }
}

// S6: fused grad + decay-update + sumsq. grid 696:
// [0,384) W2 (24 mat x 16 row-tiles), [384,640) W1 (16 x 16), [640,688) b1/b2,
// [688,696) eta/alpha w1vec.
__global__ __launch_bounds__(256) void k_s6(float* ws) {
  __shared__ float sm[64 * 20 + 8];
  float* slack = sm + 64 * 20;
  const int tid = threadIdx.x, bid = blockIdx.x;
  if (bid < 640) {
    const bool isW2 = bid < 384;
    int b, m, r0, scaleIdx;
    float* W;
    float4 fac[16];
    const float* tsrc;
    if (isW2) {
      const int bm = bid >> 4;
      b = bm / 6; m = bm % 6; r0 = (bid & 15) * 64;
      W = modBase(ws, b, m);
      scaleIdx = sidx(b, m, 2);
      tsrc = ws + OFF_DLP + ((long)b * 6 + m) * 16384;
      const float* kraw = ws + OFF_KVQ + ((long)b * 3) * 16384;
#pragma unroll
      for (int c = 0; c < 16; c++) {
        const float inv = 1.f / fmaxf(sqrtf(ws[OFF_RSSQ + (long)b * 32 + c]), 1e-12f);
        const float4 kk = *(const float4*)(kraw + (long)c * 1024 + tid * 4);
        fac[c].x = kk.x * inv; fac[c].y = kk.y * inv;
        fac[c].z = kk.z * inv; fac[c].w = kk.w * inv;
      }
    } else {
      const int id = bid - 384, bm = id >> 4;
      b = bm >> 2; m = BIGM[bm & 3]; r0 = (id & 15) * 64;
      W = modBase(ws, b, m) + 1048576;
      scaleIdx = sidx(b, m, 0);
      tsrc = ws + OFF_ERR + ((long)b * 6 + m) * 16384;
      const float* sprek = ws + OFF_SPREK + ((long)b * 6 + m) * 16384;
#pragma unroll
      for (int c = 0; c < 16; c++)
        fac[c] = *(const float4*)(sprek + (long)c * 1024 + tid * 4);
    }
    for (int f = tid; f < 1024; f += 256) {
      const int c = f >> 6, hh = f & 63;
      sm[hh * 20 + c] = tsrc[(long)c * 1024 + r0 + hh];
    }
    __syncthreads();
    const float ea = ws[OFF_EA + b], aa = ws[OFF_EA + 4 + b];
    const float ac = aa * ws[OFF_SCALE + scaleIdx];
    float ss = 0.f;
#pragma unroll 1
    for (int hh = 0; hh < 64; hh++) {
      const float4 q0 = *(const float4*)(sm + hh * 20);
      const float4 q1 = *(const float4*)(sm + hh * 20 + 4);
      const float4 q2 = *(const float4*)(sm + hh * 20 + 8);
      const float4 q3 = *(const float4*)(sm + hh * 20 + 12);
      float4 g = {0.f, 0.f, 0.f, 0.f};
#pragma unroll
      for (int c = 0; c < 16; c++) {
        const float4 qq = c < 4 ? q0 : (c < 8 ? q1 : (c < 12 ? q2 : q3));
        const float dv = (&qq.x)[c & 3];
        g.x = fmaf(dv, fac[c].x, g.x);
        g.y = fmaf(dv, fac[c].y, g.y);
        g.z = fmaf(dv, fac[c].z, g.z);
        g.w = fmaf(dv, fac[c].w, g.w);
      }
      float4* Wp = (float4*)(W + (size_t)(r0 + hh) * 1024 + tid * 4);
      float4 w = *Wp;
      w.x = fmaf(ac, w.x, -ea * g.x);
      w.y = fmaf(ac, w.y, -ea * g.y);
      w.z = fmaf(ac, w.z, -ea * g.z);
      w.w = fmaf(ac, w.w, -ea * g.w);
      *Wp = w;
      ss = fmaf(w.x, w.x, fmaf(w.y, w.y, fmaf(w.z, w.z, fmaf(w.w, w.w, ss))));
    }
    sumsqReduce(ss, slack, ws + OFF_SUMSQ + scaleIdx);
  } else if (bid < 688) {
    const int id = bid - 640;
    const int b = id / 12, r = id % 12, m = r >> 1, which = r & 1;
    const float ea = ws[OFF_EA + b], aa = ws[OFF_EA + 4 + b];
    float* vc = vecp(modBase(ws, b, m), m);
    float ss = 0.f;
    if (which == 0) {
      const int n = DOUTS[m];
      const float* errP = ws + OFF_ERR + ((long)b * 6 + m) * 16384;
      const float ac = aa * ws[OFF_SCALE + sidx(b, m, 1)];
      for (int o = tid; o < n; o += 256) {
        float gs = 0.f;
#pragma unroll
        for (int c = 0; c < 16; c++) gs += errP[c * 1024 + o];
        const float nw = fmaf(ac, vc[o], -ea * gs);
        vc[o] = nw;
        ss = fmaf(nw, nw, ss);
      }
      sumsqReduce(ss, slack, ws + OFF_SUMSQ + sidx(b, m, 1));
    } else {
      const float* dlpP = ws + OFF_DLP + ((long)b * 6 + m) * 16384;
      const float ac = aa * ws[OFF_SCALE + sidx(b, m, 3)];
      for (int h = tid; h < 1024; h += 256) {
        float gs = 0.f;
#pragma unroll
        for (int c = 0; c < 16; c++) gs += dlpP[c * 1024 + h];
        const float nw = fmaf(ac, vc[1024 + h], -ea * gs);
        vc[1024 + h] = nw;
        ss = fmaf(nw, nw, ss);
      }
      sumsqReduce(ss, slack, ws + OFF_SUMSQ + sidx(b, m, 3));
    }
  } else {
    const int e2 = bid - 688, b = e2 >> 1, m = 3 + (e2 & 1);
    const float ea = ws[OFF_EA + b], aa = ws[OFF_EA + 4 + b];
    float* vc = vecp(modBase(ws, b, m), m);
    const float* errP = ws + OFF_ERR + ((long)b * 6 + m) * 16384;
    const float* sprek = ws + OFF_SPREK + ((long)b * 6 + m) * 16384;
    const float ac = aa * ws[OFF_SCALE + sidx(b, m, 0)];
    float ss = 0.f;
    for (int h = tid; h < 1024; h += 256) {
      float gs = 0.f;
#pragma unroll
      for (int c = 0; c < 16; c++)
        gs = fmaf(errP[c * 1024], sprek[c * 1024 + h], gs);
      const float nw = fmaf(ac, vc[2048 + h], -ea * gs);
      vc[2048 + h] = nw;
      ss = fmaf(nw, nw, ss);
    }
    sumsqReduce(ss, slack, ws + OFF_SUMSQ + sidx(b, m, 0));
  }
}

// ============================ epilogue ============================

__global__ __launch_bounds__(256) void k_ln(float* ws, const float* __restrict__ g,
                                            const float* __restrict__ bb) {
  __shared__ float sm[8];
  float* p = ws + OFF_Z + (long)blockIdx.x * 1024;
  const int tid = threadIdx.x;
  float s = 0.f, s2 = 0.f;
  for (int j = tid; j < 1024; j += 256) {
    const float v = p[j];
    s += v;
    s2 = fmaf(v, v, s2);
  }
#pragma unroll
  for (int st = 32; st >= 1; st >>= 1) { s += __shfl_xor(s, st); s2 += __shfl_xor(s2, st); }
  if ((tid & 63) == 0) { sm[tid >> 6] = s; sm[4 + (tid >> 6)] = s2; }
  __syncthreads();
  const float S = sm[0] + sm[1] + sm[2] + sm[3];
  const float S2 = sm[4] + sm[5] + sm[6] + sm[7];
  const float mu = S * (1.f / 1024.f);
  const float var = S2 * (1.f / 1024.f) - mu * mu;
  const float inv = 1.f / sqrtf(var + 1e-5f);
  for (int j = tid; j < 1024; j += 256) {
    p[j] = fmaf((p[j] - mu) * inv, g[j], bb[j]);
  }
}

}  // namespace

extern "C" void kernel_launch(void* const* d_in, const int* in_sizes, int n_in,
                              void* d_out, int out_size, void* d_ws, size_t ws_size,
                              hipStream_t stream) {
  (void)in_sizes; (void)n_in; (void)out_size;
  if (ws_size < (size_t)WS_FLOATS * sizeof(float)) return;
  float* ws = (float*)d_ws;
  InPtrs ip;
  for (int i = 0; i < 31; i++) ip.p[i] = (const float*)d_in[i];

  k_probe<<<1, 64, 0, stream>>>(ws);
  k_p0<<<256, 256, 0, stream>>>(ws, ip);
  k_pc<<<5120, 256, 0, stream>>>(ws, ip);
  k_gbig<<<32768, 256, 0, stream>>>((const float*)d_in[0], (const float*)d_in[25],
                                    (const float*)d_in[26], ws + OFF_Z, ws + OFF_FLAG);

  for (int t = 0; t < 128; t++) {
    if (t) k_s0<<<1, 256, 0, stream>>>(ws);
    k_s1<<<1280, 256, 0, stream>>>(ws, t);
    k_s2<<<776, 256, 0, stream>>>(ws, t);
    k_s3<<<1792, 256, 0, stream>>>(ws);
    k_s4<<<1288, 256, 0, stream>>>(ws, t);
    k_s5<<<1056, 256, 0, stream>>>(ws);
    k_s6<<<696, 256, 0, stream>>>(ws);
  }

  k_ln<<<8192, 256, 0, stream>>>(ws, (const float*)d_in[29], (const float*)d_in[30]);
  k_gbig<<<32768, 256, 0, stream>>>(ws + OFF_Z, (const float*)d_in[27],
                                    (const float*)d_in[28], (float*)d_out, ws + OFF_FLAG);
}